// Round 12
// baseline (362.291 us; speedup 1.0000x reference)
//
#include <hip/hip_runtime.h>

// Problem constants (fixed instance):
//   B=128 graphs, N=1024 nodes/graph, F=128 in-feats, D=256 hidden, E=8192 edges/graph
#define NNODES   1024
#define NGRAPH   128
#define NTOTAL   (NNODES * NGRAPH)   // 131072
#define FEAT_IN  128
#define DHID     256
#define ECAP     (16384 + NNODES)    // CSR capacity
#define GBK      64

typedef __attribute__((ext_vector_type(8))) short bf16x8;
typedef __attribute__((ext_vector_type(4))) float f32x4;
typedef __attribute__((ext_vector_type(4))) unsigned short us4;
typedef __attribute__((ext_vector_type(8))) unsigned short us8;

__device__ __forceinline__ unsigned short f2bf(float f) {
    unsigned int u = __float_as_uint(f);
    u += 0x7fffu + ((u >> 16) & 1u);           // RNE
    return (unsigned short)(u >> 16);
}
__device__ __forceinline__ float blo(unsigned int u) { return __uint_as_float(u << 16); }
__device__ __forceinline__ float bhi(unsigned int u) { return __uint_as_float(u & 0xffff0000u); }

// Shared-memory union: GEMM staging vs builder scratch (block 0 only uses .b)
union SMU {
    struct { unsigned short sA[128 * GBK]; unsigned short sB[128 * GBK]; } g;   // 32 KB
    struct { int scnt[NNODES]; int psA[256]; int psB[256];
             float sdinv[NNODES]; float fb[NNODES]; } b;                        // 14 KB
};

// ---------------- W1 prep (no BN): Wt[n][k] = bf16(W[k][n]) ; cvec[n] = 0 ------------------------
__global__ __launch_bounds__(256) void wprep_kernel(
    const float* __restrict__ W, unsigned short* __restrict__ Wt,
    float* __restrict__ cvec, int K)
{
    const int n = blockIdx.x, k = threadIdx.x;
    if (k < K) Wt[(size_t)n * K + k] = f2bf(W[(size_t)k * DHID + n]);
    if (k == 0) cvec[n] = 0.0f;
}

// ---------------- fused BN-finalize + W prep -----------------------------------------------------
__global__ __launch_bounds__(256) void bnwprep_kernel(
    const float* __restrict__ stats, const float* __restrict__ gamma,
    const float* __restrict__ beta, const float* __restrict__ W,
    unsigned short* __restrict__ Wt, float* __restrict__ cvec)
{
    __shared__ float red[256];
    const int n = blockIdx.x, k = threadIdx.x;
    const float nn = (float)NTOTAL;
    const float mean = stats[k] / nn;
    const float var = stats[256 + k] / nn - mean * mean;
    const float sc = gamma[k] * rsqrtf(var + 1e-5f);
    const float sh = beta[k] - mean * sc;
    const float wv = W[(size_t)k * DHID + n];
    Wt[(size_t)n * DHID + k] = f2bf(sc * wv);
    red[k] = sh * wv;
    __syncthreads();
    for (int s = 128; s > 0; s >>= 1) {
        if (k < s) red[k] += red[k + s];
        __syncthreads();
    }
    if (k == 0) cvec[n] = red[0];
}

// ---------------- GEMM-1 (fp32 A, in-kernel cvt) + fused CSR builder (block 0) -------------------
__global__ __launch_bounds__(256) void gemm1_kernel(
    const float* __restrict__ x, const unsigned short* __restrict__ Wt,
    unsigned short* __restrict__ C,
    const int* __restrict__ ei, int E,
    int* __restrict__ offs, uint2* __restrict__ ecw,
    float* __restrict__ rowsum, float* __restrict__ stats)
{
    __shared__ SMU sm;
    const int t = threadIdx.x;

    if (blockIdx.x == 0) {
        // ---------- builder (256 threads, 4 nodes/thread) ----------
        #pragma unroll
        for (int i = 0; i < 4; ++i) { sm.b.scnt[t * 4 + i] = 1; stats[t + 256 * i] = 0.0f; }
        __syncthreads();
        for (int e = t; e < E; e += 256) atomicAdd(&sm.b.scnt[ei[E + e]], 1);
        __syncthreads();
        int c[4]; int ssum = 0;
        #pragma unroll
        for (int i = 0; i < 4; ++i) { c[i] = sm.b.scnt[t * 4 + i]; ssum += c[i]; }
        sm.b.psA[t] = ssum;
        __syncthreads();
        int* src = sm.b.psA; int* dst = sm.b.psB;
        for (int d = 1; d < 256; d <<= 1) {          // 8 iters (even) -> result in psA
            dst[t] = src[t] + (t >= d ? src[t - d] : 0);
            __syncthreads();
            int* tmp = src; src = dst; dst = tmp;
        }
        int run = src[t] - ssum;                     // exclusive prefix of this 4-node group
        float di[4]; int pos[4];
        #pragma unroll
        for (int i = 0; i < 4; ++i) {
            offs[t * 4 + i] = run;
            di[i] = rsqrtf((float)c[i]);
            sm.b.sdinv[t * 4 + i] = di[i];
            pos[i] = run;
            run += c[i];
        }
        if (t == 255) offs[NNODES] = run;
        __syncthreads();
        #pragma unroll
        for (int i = 0; i < 4; ++i) {                // self loop first; cursor continues after it
            ecw[pos[i]] = make_uint2((unsigned)(t * 4 + i), __float_as_uint(di[i] * di[i]));
            sm.b.scnt[t * 4 + i] = pos[i] + 1;
            sm.b.fb[t * 4 + i] = di[i] * di[i];
        }
        __syncthreads();
        for (int e = t; e < E; e += 256) {
            const int sN = ei[e], dN = ei[E + e];
            const int p = atomicAdd(&sm.b.scnt[dN], 1);
            const float wv = sm.b.sdinv[sN] * sm.b.sdinv[dN];
            ecw[p] = make_uint2((unsigned)sN, __float_as_uint(wv));
            atomicAdd(&sm.b.fb[dN], wv);
        }
        __syncthreads();
        #pragma unroll
        for (int i = 0; i < 4; ++i) rowsum[t * 4 + i] = sm.b.fb[t * 4 + i];
        return;
    }

    // ---------- GEMM path ----------
    const int bid = blockIdx.x - 1;
    const int xcd = bid & 7, kk_ = bid >> 3;
    const int m0 = ((kk_ >> 1) * 8 + xcd) * 128;     // n-tile pair of an m-panel shares an XCD
    const int n0 = (kk_ & 1) * 128;
    const int K = FEAT_IN;

    const int w = t >> 6, lane = t & 63;
    const int wr = w >> 1, wc = w & 1;
    const int lr = lane & 15, lk = lane >> 4;
    const int srow = lane >> 3;
    const int seg_src = (lane & 7) ^ srow;           // inverse-swizzled source segment

    f32x4 acc[4][4];
    #pragma unroll
    for (int i = 0; i < 4; ++i)
        #pragma unroll
        for (int j = 0; j < 4; ++j)
            acc[i][j] = (f32x4){0.f, 0.f, 0.f, 0.f};

    const int r = t >> 1, kh = (t & 1) * 32;         // A-staging: row r, k-range [kh, kh+32)
    for (int s = 0; s < 2; ++s) {                    // K=128 -> 2 steps
        if (s > 0) __syncthreads();
        #pragma unroll
        for (int i = 0; i < 4; ++i) {
            const int row = (w * 4 + i) * 8 + srow;
            const unsigned short* gb = Wt + (size_t)(n0 + row) * K + s * GBK + seg_src * 8;
            __builtin_amdgcn_global_load_lds(
                (const __attribute__((address_space(1))) unsigned int*)gb,
                (__attribute__((address_space(3))) unsigned int*)&sm.g.sB[(w * 4 + i) * 512],
                16, 0, 0);
        }
        const float* ga = x + (size_t)(m0 + r) * K + s * GBK + kh;
        #pragma unroll
        for (int j = 0; j < 4; ++j) {
            const float4 v0 = *(const float4*)(ga + j * 8);
            const float4 v1 = *(const float4*)(ga + j * 8 + 4);
            us8 o;
            o[0] = f2bf(v0.x); o[1] = f2bf(v0.y); o[2] = f2bf(v0.z); o[3] = f2bf(v0.w);
            o[4] = f2bf(v1.x); o[5] = f2bf(v1.y); o[6] = f2bf(v1.z); o[7] = f2bf(v1.w);
            const int slot = ((kh >> 3) + j) ^ (r & 7);
            *(us8*)&sm.g.sA[r * 64 + slot * 8] = o;
        }
        __syncthreads();                             // drains B vmcnt + A lds writes
        const char* pa = (const char*)sm.g.sA;
        const char* pb = (const char*)sm.g.sB;
        #pragma unroll
        for (int ks = 0; ks < 2; ++ks) {
            bf16x8 af[4], bfv[4];
            #pragma unroll
            for (int f = 0; f < 4; ++f) {
                const int ra = wr * 64 + f * 16 + lr;
                af[f] = *(const bf16x8*)(pa + ra * 128 + ((ks * 64 + lk * 16) ^ ((ra & 7) << 4)));
                const int rb = wc * 64 + f * 16 + lr;
                bfv[f] = *(const bf16x8*)(pb + rb * 128 + ((ks * 64 + lk * 16) ^ ((rb & 7) << 4)));
            }
            #pragma unroll
            for (int mf = 0; mf < 4; ++mf)
                #pragma unroll
                for (int nf = 0; nf < 4; ++nf)
                    acc[mf][nf] = __builtin_amdgcn_mfma_f32_16x16x32_bf16(
                        af[mf], bfv[nf], acc[mf][nf], 0, 0, 0);
        }
    }

    #pragma unroll
    for (int mf = 0; mf < 4; ++mf) {
        const int rbase = m0 + wr * 64 + mf * 16 + lk * 4;
        #pragma unroll
        for (int nf = 0; nf < 4; ++nf) {
            const int c = n0 + wc * 64 + nf * 16 + lr;
            #pragma unroll
            for (int rr = 0; rr < 4; ++rr)
                C[(size_t)(rbase + rr) * DHID + c] = f2bf(acc[mf][nf][rr]);
        }
    }
}

// ---------------- MFMA GEMM (layers 2/3): C[M][256] = bf16(A @ Wt^T), A bf16 ---------------------
__global__ __launch_bounds__(256) void mgemm_kernel(
    const unsigned short* __restrict__ Ain,
    const unsigned short* __restrict__ Wt,
    unsigned short* __restrict__ C, int K)
{
    __shared__ unsigned short sA[2][128 * GBK];
    __shared__ unsigned short sB[2][128 * GBK];

    const int t = threadIdx.x;
    const int bid = blockIdx.x;
    const int xcd = bid & 7, kk_ = bid >> 3;
    const int m0 = ((kk_ >> 1) * 8 + xcd) * 128;
    const int n0 = (kk_ & 1) * 128;

    const int w = t >> 6, lane = t & 63;
    const int wr = w >> 1, wc = w & 1;
    const int lr = lane & 15, lk = lane >> 4;
    const int srow = lane >> 3;
    const int seg_src = (lane & 7) ^ srow;

    f32x4 acc[4][4];
    #pragma unroll
    for (int i = 0; i < 4; ++i)
        #pragma unroll
        for (int j = 0; j < 4; ++j)
            acc[i][j] = (f32x4){0.f, 0.f, 0.f, 0.f};

    const int nsteps = K >> 6;

    auto stage = [&](int buf, int k0) {
        #pragma unroll
        for (int i = 0; i < 4; ++i) {
            const int row = (w * 4 + i) * 8 + srow;
            const unsigned short* ga = Ain + (size_t)(m0 + row) * K + k0 + seg_src * 8;
            __builtin_amdgcn_global_load_lds(
                (const __attribute__((address_space(1))) unsigned int*)ga,
                (__attribute__((address_space(3))) unsigned int*)&sA[buf][(w * 4 + i) * 512],
                16, 0, 0);
            const unsigned short* gb = Wt + (size_t)(n0 + row) * K + k0 + seg_src * 8;
            __builtin_amdgcn_global_load_lds(
                (const __attribute__((address_space(1))) unsigned int*)gb,
                (__attribute__((address_space(3))) unsigned int*)&sB[buf][(w * 4 + i) * 512],
                16, 0, 0);
        }
    };

    stage(0, 0);
    __syncthreads();
    for (int s = 0; s < nsteps; ++s) {
        if (s + 1 < nsteps) stage((s + 1) & 1, (s + 1) * GBK);
        const char* pa = (const char*)sA[s & 1];
        const char* pb = (const char*)sB[s & 1];
        #pragma unroll
        for (int ks = 0; ks < 2; ++ks) {
            bf16x8 af[4], bfv[4];
            #pragma unroll
            for (int f = 0; f < 4; ++f) {
                const int ra = wr * 64 + f * 16 + lr;
                af[f] = *(const bf16x8*)(pa + ra * 128 + ((ks * 64 + lk * 16) ^ ((ra & 7) << 4)));
                const int rb = wc * 64 + f * 16 + lr;
                bfv[f] = *(const bf16x8*)(pb + rb * 128 + ((ks * 64 + lk * 16) ^ ((rb & 7) << 4)));
            }
            #pragma unroll
            for (int mf = 0; mf < 4; ++mf)
                #pragma unroll
                for (int nf = 0; nf < 4; ++nf)
                    acc[mf][nf] = __builtin_amdgcn_mfma_f32_16x16x32_bf16(
                        af[mf], bfv[nf], acc[mf][nf], 0, 0, 0);
        }
        __syncthreads();
    }

    #pragma unroll
    for (int mf = 0; mf < 4; ++mf) {
        const int rbase = m0 + wr * 64 + mf * 16 + lk * 4;
        #pragma unroll
        for (int nf = 0; nf < 4; ++nf) {
            const int c = n0 + wc * 64 + nf * 16 + lr;
            #pragma unroll
            for (int rr = 0; rr < 4; ++rr)
                C[(size_t)(rbase + rr) * DHID + c] = f2bf(acc[mf][nf][rr]);
        }
    }
}

// ---------------- SpMM: h = relu(Anorm @ hw + rowsum*c + b), padded + paired chains --------------
// Lane l owns features 4l..4l+3 (8B uint2 gathers); wave w owns 4 of the block's 16 nodes.
// Edge lists padded in LDS to a multiple of 4 per node (weight-0, col-0 pads: exact +0.0,
// bit-identical sums) -> no scalar tails. Node PAIRS processed with interleaved chains:
// 8 independent gathers in flight per iteration (wave-uniform control, no divergence).
#define NB 16
#define ECAPB 512

template<bool STATS, bool OUTF32>
__global__ __launch_bounds__(256) void spmm_kernel(
    const unsigned short* __restrict__ hw, const float* __restrict__ bias,
    const float* __restrict__ rowsum, const float* __restrict__ cvec,
    void* __restrict__ hout, float* __restrict__ partials,
    const int* __restrict__ offs, const uint2* __restrict__ ecw)
{
    __shared__ uint2 sew[ECAPB];
    __shared__ int soff[NB + 1];
    __shared__ int po[NB + 1];
    __shared__ float spartS[4][256];
    __shared__ float spartQ[4][256];

    const int b = blockIdx.x;                 // 8192 blocks
    const int xcd = b & 7;
    const int idx = b >> 3;
    const int g  = (idx >> 6) * 8 + xcd;      // all 64 blocks of graph g on one XCD
    const int nb = (idx & 63) * NB;
    const int t = threadIdx.x;
    const int w = t >> 6, l = t & 63;
    const int f0 = l * 4;
    const unsigned short* __restrict__ hwg = hw + (size_t)g * NNODES * DHID;

    if (t <= NB) soff[t] = offs[nb + t];
    sew[t] = make_uint2(0u, 0u);              // zero-pad whole buffer (weight 0, col 0)
    sew[t + 256] = make_uint2(0u, 0u);
    __syncthreads();
    if (t == 0) {
        int run = 0;
        po[0] = 0;
        #pragma unroll
        for (int i = 0; i < NB; ++i) {
            run += (soff[i + 1] - soff[i] + 3) & ~3;
            po[i + 1] = run;
        }
    }
    __syncthreads();
    const int base = soff[0];
    const int tot = soff[NB] - base;          // ~150, padded total <= ~200 < 512
    for (int e = t; e < tot; e += 256) {
        int d = 0;
        #pragma unroll
        for (int i = 1; i < NB; ++i) d += (e >= (soff[i] - base));
        sew[po[d] + (e - (soff[d] - base))] = ecw[base + e];
    }
    __syncthreads();

    const float4 bv = *(const float4*)(bias + f0);
    const float4 cv = *(const float4*)(cvec + f0);
    float ps0=0, ps1=0, ps2=0, ps3=0, pq0=0, pq1=0, pq2=0, pq3=0;

    #pragma unroll 1
    for (int j2 = 0; j2 < 2; ++j2) {
        const int iA = w * 4 + j2 * 2;
        const int iB = iA + 1;
        const int kA0 = po[iA], cA = po[iA + 1] - kA0;
        const int kB0 = po[iB], cB = po[iB + 1] - kB0;
        const int cmin = min(cA, cB);         // both multiples of 4
        float a0=0, a1=0, a2=0, a3=0;         // node A accumulators (4 feats)
        float d0=0, d1=0, d2=0, d3=0;         // node B accumulators
        int k = 0;
        #pragma unroll 1
        for (; k < cmin; k += 4) {
            const uint2 pA0 = sew[kA0+k], pA1 = sew[kA0+k+1], pA2 = sew[kA0+k+2], pA3 = sew[kA0+k+3];
            const uint2 pB0 = sew[kB0+k], pB1 = sew[kB0+k+1], pB2 = sew[kB0+k+2], pB3 = sew[kB0+k+3];
            const uint2 uA0 = *(const uint2*)(hwg + (size_t)pA0.x * DHID + f0);
            const uint2 uB0 = *(const uint2*)(hwg + (size_t)pB0.x * DHID + f0);
            const uint2 uA1 = *(const uint2*)(hwg + (size_t)pA1.x * DHID + f0);
            const uint2 uB1 = *(const uint2*)(hwg + (size_t)pB1.x * DHID + f0);
            const uint2 uA2 = *(const uint2*)(hwg + (size_t)pA2.x * DHID + f0);
            const uint2 uB2 = *(const uint2*)(hwg + (size_t)pB2.x * DHID + f0);
            const uint2 uA3 = *(const uint2*)(hwg + (size_t)pA3.x * DHID + f0);
            const uint2 uB3 = *(const uint2*)(hwg + (size_t)pB3.x * DHID + f0);
            const float wA0 = __uint_as_float(pA0.y), wA1 = __uint_as_float(pA1.y);
            const float wA2 = __uint_as_float(pA2.y), wA3 = __uint_as_float(pA3.y);
            const float wB0 = __uint_as_float(pB0.y), wB1 = __uint_as_float(pB1.y);
            const float wB2 = __uint_as_float(pB2.y), wB3 = __uint_as_float(pB3.y);
            a0 = fmaf(wA0, blo(uA0.x), a0); a1 = fmaf(wA0, bhi(uA0.x), a1);
            a2 = fmaf(wA0, blo(uA0.y), a2); a3 = fmaf(wA0, bhi(uA0.y), a3);
            d0 = fmaf(wB0, blo(uB0.x), d0); d1 = fmaf(wB0, bhi(uB0.x), d1);
            d2 = fmaf(wB0, blo(uB0.y), d2); d3 = fmaf(wB0, bhi(uB0.y), d3);
            a0 = fmaf(wA1, blo(uA1.x), a0); a1 = fmaf(wA1, bhi(uA1.x), a1);
            a2 = fmaf(wA1, blo(uA1.y), a2); a3 = fmaf(wA1, bhi(uA1.y), a3);
            d0 = fmaf(wB1, blo(uB1.x), d0); d1 = fmaf(wB1, bhi(uB1.x), d1);
            d2 = fmaf(wB1, blo(uB1.y), d2); d3 = fmaf(wB1, bhi(uB1.y), d3);
            a0 = fmaf(wA2, blo(uA2.x), a0); a1 = fmaf(wA2, bhi(uA2.x), a1);
            a2 = fmaf(wA2, blo(uA2.y), a2); a3 = fmaf(wA2, bhi(uA2.y), a3);
            d0 = fmaf(wB2, blo(uB2.x), d0); d1 = fmaf(wB2, bhi(uB2.x), d1);
            d2 = fmaf(wB2, blo(uB2.y), d2); d3 = fmaf(wB2, bhi(uB2.y), d3);
            a0 = fmaf(wA3, blo(uA3.x), a0); a1 = fmaf(wA3, bhi(uA3.x), a1);
            a2 = fmaf(wA3, blo(uA3.y), a2); a3 = fmaf(wA3, bhi(uA3.y), a3);
            d0 = fmaf(wB3, blo(uB3.x), d0); d1 = fmaf(wB3, bhi(uB3.x), d1);
            d2 = fmaf(wB3, blo(uB3.y), d2); d3 = fmaf(wB3, bhi(uB3.y), d3);
        }
        #pragma unroll 1
        for (int ka = k; ka < cA; ka += 4) {   // drain A (multiples of 4, no tail)
            const uint2 p0 = sew[kA0+ka], p1 = sew[kA0+ka+1], p2 = sew[kA0+ka+2], p3 = sew[kA0+ka+3];
            const uint2 u0 = *(const uint2*)(hwg + (size_t)p0.x * DHID + f0);
            const uint2 u1 = *(const uint2*)(hwg + (size_t)p1.x * DHID + f0);
            const uint2 u2 = *(const uint2*)(hwg + (size_t)p2.x * DHID + f0);
            const uint2 u3 = *(const uint2*)(hwg + (size_t)p3.x * DHID + f0);
            const float w0 = __uint_as_float(p0.y), w1 = __uint_as_float(p1.y);
            const float w2 = __uint_as_float(p2.y), w3 = __uint_as_float(p3.y);
            a0 = fmaf(w0, blo(u0.x), a0); a1 = fmaf(w0, bhi(u0.x), a1);
            a2 = fmaf(w0, blo(u0.y), a2); a3 = fmaf(w0, bhi(u0.y), a3);
            a0 = fmaf(w1, blo(u1.x), a0); a1 = fmaf(w1, bhi(u1.x), a1);
            a2 = fmaf(w1, blo(u1.y), a2); a3 = fmaf(w1, bhi(u1.y), a3);
            a0 = fmaf(w2, blo(u2.x), a0); a1 = fmaf(w2, bhi(u2.x), a1);
            a2 = fmaf(w2, blo(u2.y), a2); a3 = fmaf(w2, bhi(u2.y), a3);
            a0 = fmaf(w3, blo(u3.x), a0); a1 = fmaf(w3, bhi(u3.x), a1);
            a2 = fmaf(w3, blo(u3.y), a2); a3 = fmaf(w3, bhi(u3.y), a3);
        }
        #pragma unroll 1
        for (int kb = k; kb < cB; kb += 4) {   // drain B
            const uint2 p0 = sew[kB0+kb], p1 = sew[kB0+kb+1], p2 = sew[kB0+kb+2], p3 = sew[kB0+kb+3];
            const uint2 u0 = *(const uint2*)(hwg + (size_t)p0.x * DHID + f0);
            const uint2 u1 = *(const uint2*)(hwg + (size_t)p1.x * DHID + f0);
            const uint2 u2 = *(const uint2*)(hwg + (size_t)p2.x * DHID + f0);
            const uint2 u3 = *(const uint2*)(hwg + (size_t)p3.x * DHID + f0);
            const float w0 = __uint_as_float(p0.y), w1 = __uint_as_float(p1.y);
            const float w2 = __uint_as_float(p2.y), w3 = __uint_as_float(p3.y);
            d0 = fmaf(w0, blo(u0.x), d0); d1 = fmaf(w0, bhi(u0.x), d1);
            d2 = fmaf(w0, blo(u0.y), d2); d3 = fmaf(w0, bhi(u0.y), d3);
            d0 = fmaf(w1, blo(u1.x), d0); d1 = fmaf(w1, bhi(u1.x), d1);
            d2 = fmaf(w1, blo(u1.y), d2); d3 = fmaf(w1, bhi(u1.y), d3);
            d0 = fmaf(w2, blo(u2.x), d0); d1 = fmaf(w2, bhi(u2.x), d1);
            d2 = fmaf(w2, blo(u2.y), d2); d3 = fmaf(w2, bhi(u2.y), d3);
            d0 = fmaf(w3, blo(u3.x), d0); d1 = fmaf(w3, bhi(u3.x), d1);
            d2 = fmaf(w3, blo(u3.y), d2); d3 = fmaf(w3, bhi(u3.y), d3);
        }

        // epilogue node A
        {
            const int i = iA;
            const float rs = rowsum[nb + i];
            const float v0 = fmaxf(fmaf(rs, cv.x, a0) + bv.x, 0.0f);
            const float v1 = fmaxf(fmaf(rs, cv.y, a1) + bv.y, 0.0f);
            const float v2 = fmaxf(fmaf(rs, cv.z, a2) + bv.z, 0.0f);
            const float v3 = fmaxf(fmaf(rs, cv.w, a3) + bv.w, 0.0f);
            const size_t orow = (size_t)g * NNODES + nb + i;
            if (OUTF32) {
                *(float4*)((float*)hout + orow * DHID + f0) = make_float4(v0, v1, v2, v3);
            } else {
                us4 o; o[0] = f2bf(v0); o[1] = f2bf(v1); o[2] = f2bf(v2); o[3] = f2bf(v3);
                *(us4*)((unsigned short*)hout + orow * DHID + f0) = o;
            }
            if (STATS) {
                ps0 += v0; ps1 += v1; ps2 += v2; ps3 += v3;
                pq0 += v0*v0; pq1 += v1*v1; pq2 += v2*v2; pq3 += v3*v3;
            }
        }
        // epilogue node B
        {
            const int i = iB;
            const float rs = rowsum[nb + i];
            const float v0 = fmaxf(fmaf(rs, cv.x, d0) + bv.x, 0.0f);
            const float v1 = fmaxf(fmaf(rs, cv.y, d1) + bv.y, 0.0f);
            const float v2 = fmaxf(fmaf(rs, cv.z, d2) + bv.z, 0.0f);
            const float v3 = fmaxf(fmaf(rs, cv.w, d3) + bv.w, 0.0f);
            const size_t orow = (size_t)g * NNODES + nb + i;
            if (OUTF32) {
                *(float4*)((float*)hout + orow * DHID + f0) = make_float4(v0, v1, v2, v3);
            } else {
                us4 o; o[0] = f2bf(v0); o[1] = f2bf(v1); o[2] = f2bf(v2); o[3] = f2bf(v3);
                *(us4*)((unsigned short*)hout + orow * DHID + f0) = o;
            }
            if (STATS) {
                ps0 += v0; ps1 += v1; ps2 += v2; ps3 += v3;
                pq0 += v0*v0; pq1 += v1*v1; pq2 += v2*v2; pq3 += v3*v3;
            }
        }
    }

    if (STATS) {
        spartS[w][f0+0] = ps0; spartS[w][f0+1] = ps1; spartS[w][f0+2] = ps2; spartS[w][f0+3] = ps3;
        spartQ[w][f0+0] = pq0; spartQ[w][f0+1] = pq1; spartQ[w][f0+2] = pq2; spartQ[w][f0+3] = pq3;
        __syncthreads();
        const float ss = spartS[0][t] + spartS[1][t] + spartS[2][t] + spartS[3][t];
        const float sq = spartQ[0][t] + spartQ[1][t] + spartQ[2][t] + spartQ[3][t];
        partials[(size_t)b * 512 + t] = ss;
        partials[(size_t)b * 512 + 256 + t] = sq;
    }
}

// ---------------- stats reduce ------------------------------------------------------------------
__global__ __launch_bounds__(256) void reduce_kernel(
    const float* __restrict__ partials, float* __restrict__ stats, int P)
{
    const int t = threadIdx.x;
    const int per = P / gridDim.x;
    const int p0 = blockIdx.x * per;
    float s = 0.0f, q = 0.0f;
    for (int p = p0; p < p0 + per; ++p) {
        s += partials[(size_t)p * 512 + t];
        q += partials[(size_t)p * 512 + 256 + t];
    }
    atomicAdd(&stats[t], s);
    atomicAdd(&stats[256 + t], q);
}

// ---------------- launch -------------------------------------------------------------------------
extern "C" void kernel_launch(void* const* d_in, const int* in_sizes, int n_in,
                              void* d_out, int out_size, void* d_ws, size_t ws_size,
                              hipStream_t stream)
{
    const float* x      = (const float*)d_in[0];
    const int*   ei     = (const int*)d_in[1];
    const float* W1     = (const float*)d_in[3];
    const float* b1     = (const float*)d_in[4];
    const float* W2     = (const float*)d_in[5];
    const float* b2     = (const float*)d_in[6];
    const float* W3     = (const float*)d_in[7];
    const float* b3     = (const float*)d_in[8];
    const float* gamma1 = (const float*)d_in[9];
    const float* beta1  = (const float*)d_in[10];
    const float* gamma2 = (const float*)d_in[11];
    const float* beta2  = (const float*)d_in[12];
    float* out = (float*)d_out;

    const int E = in_sizes[1] / 2;   // 8192

    // workspace layout (total ~152 MB)
    char* w = (char*)d_ws;
    unsigned short* hA = (unsigned short*)w;                 // h bf16 (67 MB)
    unsigned short* hw = (unsigned short*)(w + 67108864);    // 67 MB
    float* partials    = (float*)(w + 134217728);            // 16.8 MB
    char* meta = w + 150994944;
    int*   offs   = (int*)meta;            meta += 4352;
    uint2* ecw    = (uint2*)meta;          meta += ECAP * 8;
    float* stats1 = (float*)meta;          meta += 512 * 4;   // stats1+stats2 contiguous (zeroed by builder)
    float* stats2 = (float*)meta;          meta += 512 * 4;
    float* rowsum = (float*)meta;          meta += NNODES * 4;
    float* cvec1  = (float*)meta;          meta += 256 * 4;
    float* cvec2  = (float*)meta;          meta += 256 * 4;
    float* cvec3  = (float*)meta;          meta += 256 * 4;
    unsigned short* wt1 = (unsigned short*)meta;  meta += 256 * 128 * 2;
    unsigned short* wt2 = (unsigned short*)meta;  meta += 256 * 256 * 2;
    unsigned short* wt3 = (unsigned short*)meta;  meta += 256 * 256 * 2;

    const int GG = 2048;                 // GEMM blocks (pairing swizzle decoded in-kernel)
    const int P  = NTOTAL / NB;          // 8192

    wprep_kernel<<<DHID, 256, 0, stream>>>(W1, wt1, cvec1, FEAT_IN);

    // Layer 1: GEMM (x fp32 converted in-kernel) + CSR builder fused as block 0
    gemm1_kernel<<<GG + 1, 256, 0, stream>>>(x, wt1, hw, ei, E, offs, ecw, rowsum, stats1);
    spmm_kernel<true, false><<<P, 256, 0, stream>>>(hw, b1, rowsum, cvec1, hA, partials, offs, ecw);
    reduce_kernel<<<64, 256, 0, stream>>>(partials, stats1, P);
    bnwprep_kernel<<<DHID, 256, 0, stream>>>(stats1, gamma1, beta1, W2, wt2, cvec2);

    // Layer 2
    mgemm_kernel<<<GG, 256, 0, stream>>>(hA, wt2, hw, DHID);
    spmm_kernel<true, false><<<P, 256, 0, stream>>>(hw, b2, rowsum, cvec2, hA, partials, offs, ecw);
    reduce_kernel<<<64, 256, 0, stream>>>(partials, stats2, P);
    bnwprep_kernel<<<DHID, 256, 0, stream>>>(stats2, gamma2, beta2, W3, wt3, cvec3);

    // Layer 3 (fp32 output, no stats)
    mgemm_kernel<<<GG, 256, 0, stream>>>(hA, wt3, hw, DHID);
    spmm_kernel<false, true><<<P, 256, 0, stream>>>(hw, b3, rowsum, cvec3, out, nullptr, offs, ecw);
}

// Round 13
// 289.995 us; speedup vs baseline: 1.2493x; 1.2493x over previous
//
#include <hip/hip_runtime.h>

// Problem constants (fixed instance):
//   B=128 graphs, N=1024 nodes/graph, F=128 in-feats, D=256 hidden, E=8192 edges/graph
#define NNODES   1024
#define NGRAPH   128
#define NTOTAL   (NNODES * NGRAPH)   // 131072
#define FEAT_IN  128
#define DHID     256
#define ECAP     (16384 + NNODES)    // CSR capacity
#define GBK      64

typedef __attribute__((ext_vector_type(8))) short bf16x8;
typedef __attribute__((ext_vector_type(4))) float f32x4;
typedef __attribute__((ext_vector_type(4))) unsigned short us4;
typedef __attribute__((ext_vector_type(8))) unsigned short us8;

__device__ __forceinline__ unsigned short f2bf(float f) {
    unsigned int u = __float_as_uint(f);
    u += 0x7fffu + ((u >> 16) & 1u);           // RNE
    return (unsigned short)(u >> 16);
}
__device__ __forceinline__ float blo(unsigned int u) { return __uint_as_float(u << 16); }
__device__ __forceinline__ float bhi(unsigned int u) { return __uint_as_float(u & 0xffff0000u); }

// Shared-memory union: GEMM staging vs builder scratch (block 0 only uses .b)
union SMU {
    struct { unsigned short sA[128 * GBK]; unsigned short sB[128 * GBK]; } g;   // 32 KB
    struct { int scnt[NNODES]; int psA[256]; int psB[256];
             float sdinv[NNODES]; float fb[NNODES]; } b;                        // 14 KB
};

// ---------------- W1 prep (no BN): Wt[n][k] = bf16(W[k][n]) ; cvec[n] = 0 ------------------------
__global__ __launch_bounds__(256) void wprep_kernel(
    const float* __restrict__ W, unsigned short* __restrict__ Wt,
    float* __restrict__ cvec, int K)
{
    const int n = blockIdx.x, k = threadIdx.x;
    if (k < K) Wt[(size_t)n * K + k] = f2bf(W[(size_t)k * DHID + n]);
    if (k == 0) cvec[n] = 0.0f;
}

// ---------------- fused 64-slot stats reduce + BN-finalize + W prep ------------------------------
// p64: 64 slots x 512 floats (sum | sumsq), accumulated atomically by spmm blocks.
__global__ __launch_bounds__(256) void bnwprep_kernel(
    const float* __restrict__ p64, const float* __restrict__ gamma,
    const float* __restrict__ beta, const float* __restrict__ W,
    unsigned short* __restrict__ Wt, float* __restrict__ cvec)
{
    __shared__ float red[256];
    const int n = blockIdx.x, k = threadIdx.x;
    float s = 0.0f, q = 0.0f;
    #pragma unroll
    for (int p = 0; p < 64; ++p) {
        s += p64[p * 512 + k];
        q += p64[p * 512 + 256 + k];
    }
    const float nn = (float)NTOTAL;
    const float mean = s / nn;
    const float var = q / nn - mean * mean;
    const float sc = gamma[k] * rsqrtf(var + 1e-5f);
    const float sh = beta[k] - mean * sc;
    const float wv = W[(size_t)k * DHID + n];
    Wt[(size_t)n * DHID + k] = f2bf(sc * wv);
    red[k] = sh * wv;
    __syncthreads();
    for (int st = 128; st > 0; st >>= 1) {
        if (k < st) red[k] += red[k + st];
        __syncthreads();
    }
    if (k == 0) cvec[n] = red[0];
}

// ---------------- GEMM-1 (fp32 A, in-kernel cvt) + fused CSR builder (block 0) -------------------
__global__ __launch_bounds__(256) void gemm1_kernel(
    const float* __restrict__ x, const unsigned short* __restrict__ Wt,
    unsigned short* __restrict__ C,
    const int* __restrict__ ei, int E,
    int* __restrict__ offs, uint2* __restrict__ ecw,
    float* __restrict__ rowsum)
{
    __shared__ SMU sm;
    const int t = threadIdx.x;

    if (blockIdx.x == 0) {
        // ---------- builder (256 threads, 4 nodes/thread) ----------
        #pragma unroll
        for (int i = 0; i < 4; ++i) sm.b.scnt[t * 4 + i] = 1;
        __syncthreads();
        for (int e = t; e < E; e += 256) atomicAdd(&sm.b.scnt[ei[E + e]], 1);
        __syncthreads();
        int c[4]; int ssum = 0;
        #pragma unroll
        for (int i = 0; i < 4; ++i) { c[i] = sm.b.scnt[t * 4 + i]; ssum += c[i]; }
        sm.b.psA[t] = ssum;
        __syncthreads();
        int* src = sm.b.psA; int* dst = sm.b.psB;
        for (int d = 1; d < 256; d <<= 1) {          // 8 iters (even) -> result in psA
            dst[t] = src[t] + (t >= d ? src[t - d] : 0);
            __syncthreads();
            int* tmp = src; src = dst; dst = tmp;
        }
        int run = src[t] - ssum;                     // exclusive prefix of this 4-node group
        float di[4]; int pos[4];
        #pragma unroll
        for (int i = 0; i < 4; ++i) {
            offs[t * 4 + i] = run;
            di[i] = rsqrtf((float)c[i]);
            sm.b.sdinv[t * 4 + i] = di[i];
            pos[i] = run;
            run += c[i];
        }
        if (t == 255) offs[NNODES] = run;
        __syncthreads();
        #pragma unroll
        for (int i = 0; i < 4; ++i) {                // self loop first; cursor continues after it
            ecw[pos[i]] = make_uint2((unsigned)(t * 4 + i), __float_as_uint(di[i] * di[i]));
            sm.b.scnt[t * 4 + i] = pos[i] + 1;
            sm.b.fb[t * 4 + i] = di[i] * di[i];
        }
        __syncthreads();
        for (int e = t; e < E; e += 256) {
            const int sN = ei[e], dN = ei[E + e];
            const int p = atomicAdd(&sm.b.scnt[dN], 1);
            const float wv = sm.b.sdinv[sN] * sm.b.sdinv[dN];
            ecw[p] = make_uint2((unsigned)sN, __float_as_uint(wv));
            atomicAdd(&sm.b.fb[dN], wv);
        }
        __syncthreads();
        #pragma unroll
        for (int i = 0; i < 4; ++i) rowsum[t * 4 + i] = sm.b.fb[t * 4 + i];
        return;
    }

    // ---------- GEMM path ----------
    const int bid = blockIdx.x - 1;
    const int xcd = bid & 7, kk_ = bid >> 3;
    const int m0 = ((kk_ >> 1) * 8 + xcd) * 128;     // n-tile pair of an m-panel shares an XCD
    const int n0 = (kk_ & 1) * 128;
    const int K = FEAT_IN;

    const int w = t >> 6, lane = t & 63;
    const int wr = w >> 1, wc = w & 1;
    const int lr = lane & 15, lk = lane >> 4;
    const int srow = lane >> 3;
    const int seg_src = (lane & 7) ^ srow;           // inverse-swizzled source segment

    f32x4 acc[4][4];
    #pragma unroll
    for (int i = 0; i < 4; ++i)
        #pragma unroll
        for (int j = 0; j < 4; ++j)
            acc[i][j] = (f32x4){0.f, 0.f, 0.f, 0.f};

    const int r = t >> 1, kh = (t & 1) * 32;         // A-staging: row r, k-range [kh, kh+32)
    for (int s = 0; s < 2; ++s) {                    // K=128 -> 2 steps
        if (s > 0) __syncthreads();
        #pragma unroll
        for (int i = 0; i < 4; ++i) {
            const int row = (w * 4 + i) * 8 + srow;
            const unsigned short* gb = Wt + (size_t)(n0 + row) * K + s * GBK + seg_src * 8;
            __builtin_amdgcn_global_load_lds(
                (const __attribute__((address_space(1))) unsigned int*)gb,
                (__attribute__((address_space(3))) unsigned int*)&sm.g.sB[(w * 4 + i) * 512],
                16, 0, 0);
        }
        const float* ga = x + (size_t)(m0 + r) * K + s * GBK + kh;
        #pragma unroll
        for (int j = 0; j < 4; ++j) {
            const float4 v0 = *(const float4*)(ga + j * 8);
            const float4 v1 = *(const float4*)(ga + j * 8 + 4);
            us8 o;
            o[0] = f2bf(v0.x); o[1] = f2bf(v0.y); o[2] = f2bf(v0.z); o[3] = f2bf(v0.w);
            o[4] = f2bf(v1.x); o[5] = f2bf(v1.y); o[6] = f2bf(v1.z); o[7] = f2bf(v1.w);
            const int slot = ((kh >> 3) + j) ^ (r & 7);
            *(us8*)&sm.g.sA[r * 64 + slot * 8] = o;
        }
        __syncthreads();                             // drains B vmcnt + A lds writes
        const char* pa = (const char*)sm.g.sA;
        const char* pb = (const char*)sm.g.sB;
        #pragma unroll
        for (int ks = 0; ks < 2; ++ks) {
            bf16x8 af[4], bfv[4];
            #pragma unroll
            for (int f = 0; f < 4; ++f) {
                const int ra = wr * 64 + f * 16 + lr;
                af[f] = *(const bf16x8*)(pa + ra * 128 + ((ks * 64 + lk * 16) ^ ((ra & 7) << 4)));
                const int rb = wc * 64 + f * 16 + lr;
                bfv[f] = *(const bf16x8*)(pb + rb * 128 + ((ks * 64 + lk * 16) ^ ((rb & 7) << 4)));
            }
            #pragma unroll
            for (int mf = 0; mf < 4; ++mf)
                #pragma unroll
                for (int nf = 0; nf < 4; ++nf)
                    acc[mf][nf] = __builtin_amdgcn_mfma_f32_16x16x32_bf16(
                        af[mf], bfv[nf], acc[mf][nf], 0, 0, 0);
        }
    }

    #pragma unroll
    for (int mf = 0; mf < 4; ++mf) {
        const int rbase = m0 + wr * 64 + mf * 16 + lk * 4;
        #pragma unroll
        for (int nf = 0; nf < 4; ++nf) {
            const int c = n0 + wc * 64 + nf * 16 + lr;
            #pragma unroll
            for (int rr = 0; rr < 4; ++rr)
                C[(size_t)(rbase + rr) * DHID + c] = f2bf(acc[mf][nf][rr]);
        }
    }
}

// ---------------- MFMA GEMM (layers 2/3): C[M][256] = bf16(A @ Wt^T), A bf16 ---------------------
__global__ __launch_bounds__(256) void mgemm_kernel(
    const unsigned short* __restrict__ Ain,
    const unsigned short* __restrict__ Wt,
    unsigned short* __restrict__ C, int K)
{
    __shared__ unsigned short sA[2][128 * GBK];
    __shared__ unsigned short sB[2][128 * GBK];

    const int t = threadIdx.x;
    const int bid = blockIdx.x;
    const int xcd = bid & 7, kk_ = bid >> 3;
    const int m0 = ((kk_ >> 1) * 8 + xcd) * 128;
    const int n0 = (kk_ & 1) * 128;

    const int w = t >> 6, lane = t & 63;
    const int wr = w >> 1, wc = w & 1;
    const int lr = lane & 15, lk = lane >> 4;
    const int srow = lane >> 3;
    const int seg_src = (lane & 7) ^ srow;

    f32x4 acc[4][4];
    #pragma unroll
    for (int i = 0; i < 4; ++i)
        #pragma unroll
        for (int j = 0; j < 4; ++j)
            acc[i][j] = (f32x4){0.f, 0.f, 0.f, 0.f};

    const int nsteps = K >> 6;

    auto stage = [&](int buf, int k0) {
        #pragma unroll
        for (int i = 0; i < 4; ++i) {
            const int row = (w * 4 + i) * 8 + srow;
            const unsigned short* ga = Ain + (size_t)(m0 + row) * K + k0 + seg_src * 8;
            __builtin_amdgcn_global_load_lds(
                (const __attribute__((address_space(1))) unsigned int*)ga,
                (__attribute__((address_space(3))) unsigned int*)&sA[buf][(w * 4 + i) * 512],
                16, 0, 0);
            const unsigned short* gb = Wt + (size_t)(n0 + row) * K + k0 + seg_src * 8;
            __builtin_amdgcn_global_load_lds(
                (const __attribute__((address_space(1))) unsigned int*)gb,
                (__attribute__((address_space(3))) unsigned int*)&sB[buf][(w * 4 + i) * 512],
                16, 0, 0);
        }
    };

    stage(0, 0);
    __syncthreads();
    for (int s = 0; s < nsteps; ++s) {
        if (s + 1 < nsteps) stage((s + 1) & 1, (s + 1) * GBK);
        const char* pa = (const char*)sA[s & 1];
        const char* pb = (const char*)sB[s & 1];
        #pragma unroll
        for (int ks = 0; ks < 2; ++ks) {
            bf16x8 af[4], bfv[4];
            #pragma unroll
            for (int f = 0; f < 4; ++f) {
                const int ra = wr * 64 + f * 16 + lr;
                af[f] = *(const bf16x8*)(pa + ra * 128 + ((ks * 64 + lk * 16) ^ ((ra & 7) << 4)));
                const int rb = wc * 64 + f * 16 + lr;
                bfv[f] = *(const bf16x8*)(pb + rb * 128 + ((ks * 64 + lk * 16) ^ ((rb & 7) << 4)));
            }
            #pragma unroll
            for (int mf = 0; mf < 4; ++mf)
                #pragma unroll
                for (int nf = 0; nf < 4; ++nf)
                    acc[mf][nf] = __builtin_amdgcn_mfma_f32_16x16x32_bf16(
                        af[mf], bfv[nf], acc[mf][nf], 0, 0, 0);
        }
        __syncthreads();
    }

    #pragma unroll
    for (int mf = 0; mf < 4; ++mf) {
        const int rbase = m0 + wr * 64 + mf * 16 + lk * 4;
        #pragma unroll
        for (int nf = 0; nf < 4; ++nf) {
            const int c = n0 + wc * 64 + nf * 16 + lr;
            #pragma unroll
            for (int rr = 0; rr < 4; ++rr)
                C[(size_t)(rbase + rr) * DHID + c] = f2bf(acc[mf][nf][rr]);
        }
    }
}

// ---------------- SpMM: h = relu(Anorm @ hw + rowsum*c + b), vectorized 4-feat/lane --------------
// Lane l owns features 4l..4l+3 (8B uint2 loads); wave w owns 4 of the block's 16 nodes.
// Edge metadata packed (col,weight) in one uint2: single ds_read_b64 per edge.
// XCD-affine graph mapping keeps each graph's hw slab in one L2.
// Stats: per-block sums atomically accumulated into 64-slot p64 (128 adds/address).
#define NB 16
#define ECAPB 512

template<bool STATS, bool OUTF32>
__global__ __launch_bounds__(256) void spmm_kernel(
    const unsigned short* __restrict__ hw, const float* __restrict__ bias,
    const float* __restrict__ rowsum, const float* __restrict__ cvec,
    void* __restrict__ hout, float* __restrict__ p64,
    const int* __restrict__ offs, const uint2* __restrict__ ecw)
{
    __shared__ uint2 sew[ECAPB];
    __shared__ int soff[NB + 1];
    __shared__ float spartS[4][256];
    __shared__ float spartQ[4][256];

    const int b = blockIdx.x;                 // 8192 blocks
    const int xcd = b & 7;
    const int idx = b >> 3;
    const int g  = (idx >> 6) * 8 + xcd;      // all 64 blocks of graph g on one XCD
    const int nb = (idx & 63) * NB;
    const int t = threadIdx.x;
    const int w = t >> 6, l = t & 63;
    const int f0 = l * 4;
    const unsigned short* __restrict__ hwg = hw + (size_t)g * NNODES * DHID;

    if (t <= NB) soff[t] = offs[nb + t];
    __syncthreads();
    const int base = soff[0];
    const int tot = soff[NB] - base;          // ~150, cap 512
    for (int e = t; e < tot; e += 256) sew[e] = ecw[base + e];
    __syncthreads();

    const float4 bv = *(const float4*)(bias + f0);
    const float4 cv = *(const float4*)(cvec + f0);
    float ps0=0, ps1=0, ps2=0, ps3=0, pq0=0, pq1=0, pq2=0, pq3=0;

    #pragma unroll 1
    for (int j = 0; j < 4; ++j) {
        const int i = w * 4 + j;
        const int s = soff[i] - base, e = soff[i + 1] - base;
        const float rs = rowsum[nb + i];
        float a0=0, a1=0, a2=0, a3=0;
        int k = s;
        #pragma unroll 1
        for (; k + 4 <= e; k += 4) {
            const uint2 p0 = sew[k+0], p1 = sew[k+1], p2 = sew[k+2], p3 = sew[k+3];
            const uint2 u0 = *(const uint2*)(hwg + (size_t)p0.x * DHID + f0);
            const uint2 u1 = *(const uint2*)(hwg + (size_t)p1.x * DHID + f0);
            const uint2 u2 = *(const uint2*)(hwg + (size_t)p2.x * DHID + f0);
            const uint2 u3 = *(const uint2*)(hwg + (size_t)p3.x * DHID + f0);
            const float w0 = __uint_as_float(p0.y), w1 = __uint_as_float(p1.y);
            const float w2 = __uint_as_float(p2.y), w3 = __uint_as_float(p3.y);
            a0 = fmaf(w0, blo(u0.x), a0); a1 = fmaf(w0, bhi(u0.x), a1);
            a2 = fmaf(w0, blo(u0.y), a2); a3 = fmaf(w0, bhi(u0.y), a3);
            a0 = fmaf(w1, blo(u1.x), a0); a1 = fmaf(w1, bhi(u1.x), a1);
            a2 = fmaf(w1, blo(u1.y), a2); a3 = fmaf(w1, bhi(u1.y), a3);
            a0 = fmaf(w2, blo(u2.x), a0); a1 = fmaf(w2, bhi(u2.x), a1);
            a2 = fmaf(w2, blo(u2.y), a2); a3 = fmaf(w2, bhi(u2.y), a3);
            a0 = fmaf(w3, blo(u3.x), a0); a1 = fmaf(w3, bhi(u3.x), a1);
            a2 = fmaf(w3, blo(u3.y), a2); a3 = fmaf(w3, bhi(u3.y), a3);
        }
        #pragma unroll 1
        for (; k < e; ++k) {
            const uint2 p = sew[k];
            const uint2 u = *(const uint2*)(hwg + (size_t)p.x * DHID + f0);
            const float wk = __uint_as_float(p.y);
            a0 = fmaf(wk, blo(u.x), a0); a1 = fmaf(wk, bhi(u.x), a1);
            a2 = fmaf(wk, blo(u.y), a2); a3 = fmaf(wk, bhi(u.y), a3);
        }

        const float v0 = fmaxf(fmaf(rs, cv.x, a0) + bv.x, 0.0f);
        const float v1 = fmaxf(fmaf(rs, cv.y, a1) + bv.y, 0.0f);
        const float v2 = fmaxf(fmaf(rs, cv.z, a2) + bv.z, 0.0f);
        const float v3 = fmaxf(fmaf(rs, cv.w, a3) + bv.w, 0.0f);
        const size_t orow = (size_t)g * NNODES + nb + i;
        if (OUTF32) {
            *(float4*)((float*)hout + orow * DHID + f0) = make_float4(v0, v1, v2, v3);
        } else {
            us4 o; o[0] = f2bf(v0); o[1] = f2bf(v1); o[2] = f2bf(v2); o[3] = f2bf(v3);
            *(us4*)((unsigned short*)hout + orow * DHID + f0) = o;
        }
        if (STATS) {
            ps0 += v0; ps1 += v1; ps2 += v2; ps3 += v3;
            pq0 += v0*v0; pq1 += v1*v1; pq2 += v2*v2; pq3 += v3*v3;
        }
    }

    if (STATS) {
        spartS[w][f0+0] = ps0; spartS[w][f0+1] = ps1; spartS[w][f0+2] = ps2; spartS[w][f0+3] = ps3;
        spartQ[w][f0+0] = pq0; spartQ[w][f0+1] = pq1; spartQ[w][f0+2] = pq2; spartQ[w][f0+3] = pq3;
        __syncthreads();
        const float ss = spartS[0][t] + spartS[1][t] + spartS[2][t] + spartS[3][t];
        const float sq = spartQ[0][t] + spartQ[1][t] + spartQ[2][t] + spartQ[3][t];
        float* slot = p64 + (size_t)(b & 63) * 512;
        atomicAdd(&slot[t], ss);
        atomicAdd(&slot[256 + t], sq);
    }
}

// ---------------- launch -------------------------------------------------------------------------
extern "C" void kernel_launch(void* const* d_in, const int* in_sizes, int n_in,
                              void* d_out, int out_size, void* d_ws, size_t ws_size,
                              hipStream_t stream)
{
    const float* x      = (const float*)d_in[0];
    const int*   ei     = (const int*)d_in[1];
    const float* W1     = (const float*)d_in[3];
    const float* b1     = (const float*)d_in[4];
    const float* W2     = (const float*)d_in[5];
    const float* b2     = (const float*)d_in[6];
    const float* W3     = (const float*)d_in[7];
    const float* b3     = (const float*)d_in[8];
    const float* gamma1 = (const float*)d_in[9];
    const float* beta1  = (const float*)d_in[10];
    const float* gamma2 = (const float*)d_in[11];
    const float* beta2  = (const float*)d_in[12];
    float* out = (float*)d_out;

    const int E = in_sizes[1] / 2;   // 8192

    // workspace layout (total ~135 MB + meta)
    char* w = (char*)d_ws;
    unsigned short* hA = (unsigned short*)w;                 // h bf16 (67 MB)
    unsigned short* hw = (unsigned short*)(w + 67108864);    // 67 MB
    char* meta = w + 134217728;
    float* p64a   = (float*)meta;          meta += 64 * 512 * 4;   // layer-1 stats slots
    float* p64b   = (float*)meta;          meta += 64 * 512 * 4;   // layer-2 stats slots
    int*   offs   = (int*)meta;            meta += 4352;
    uint2* ecw    = (uint2*)meta;          meta += ECAP * 8;
    float* rowsum = (float*)meta;          meta += NNODES * 4;
    float* cvec1  = (float*)meta;          meta += 256 * 4;
    float* cvec2  = (float*)meta;          meta += 256 * 4;
    float* cvec3  = (float*)meta;          meta += 256 * 4;
    unsigned short* wt1 = (unsigned short*)meta;  meta += 256 * 128 * 2;
    unsigned short* wt2 = (unsigned short*)meta;  meta += 256 * 256 * 2;
    unsigned short* wt3 = (unsigned short*)meta;  meta += 256 * 256 * 2;

    const int GG = 2048;                 // GEMM blocks (pairing swizzle decoded in-kernel)
    const int P  = NTOTAL / NB;          // 8192

    hipMemsetAsync(p64a, 0, 2 * 64 * 512 * 4, stream);   // zero both stats slabs (128 KB)
    wprep_kernel<<<DHID, 256, 0, stream>>>(W1, wt1, cvec1, FEAT_IN);

    // Layer 1: GEMM (x fp32 converted in-kernel) + CSR builder fused as block 0
    gemm1_kernel<<<GG + 1, 256, 0, stream>>>(x, wt1, hw, ei, E, offs, ecw, rowsum);
    spmm_kernel<true, false><<<P, 256, 0, stream>>>(hw, b1, rowsum, cvec1, hA, p64a, offs, ecw);
    bnwprep_kernel<<<DHID, 256, 0, stream>>>(p64a, gamma1, beta1, W2, wt2, cvec2);

    // Layer 2
    mgemm_kernel<<<GG, 256, 0, stream>>>(hA, wt2, hw, DHID);
    spmm_kernel<true, false><<<P, 256, 0, stream>>>(hw, b2, rowsum, cvec2, hA, p64b, offs, ecw);
    bnwprep_kernel<<<DHID, 256, 0, stream>>>(p64b, gamma2, beta2, W3, wt3, cvec3);

    // Layer 3 (fp32 output, no stats)
    mgemm_kernel<<<GG, 256, 0, stream>>>(hA, wt3, hw, DHID);
    spmm_kernel<false, true><<<P, 256, 0, stream>>>(hw, b3, rowsum, cvec3, out, nullptr, offs, ecw);
}

// Round 14
// 289.575 us; speedup vs baseline: 1.2511x; 1.0014x over previous
//
#include <hip/hip_runtime.h>

// Problem constants (fixed instance):
//   B=128 graphs, N=1024 nodes/graph, F=128 in-feats, D=256 hidden, E=8192 edges/graph
#define NNODES   1024
#define NGRAPH   128
#define NTOTAL   (NNODES * NGRAPH)   // 131072
#define FEAT_IN  128
#define DHID     256
#define ECAP     (16384 + NNODES)    // CSR capacity
#define GBK      64

typedef __attribute__((ext_vector_type(8))) short bf16x8;
typedef __attribute__((ext_vector_type(4))) float f32x4;
typedef __attribute__((ext_vector_type(4))) unsigned short us4;
typedef __attribute__((ext_vector_type(8))) unsigned short us8;

__device__ __forceinline__ unsigned short f2bf(float f) {
    unsigned int u = __float_as_uint(f);
    u += 0x7fffu + ((u >> 16) & 1u);           // RNE
    return (unsigned short)(u >> 16);
}
__device__ __forceinline__ float blo(unsigned int u) { return __uint_as_float(u << 16); }
__device__ __forceinline__ float bhi(unsigned int u) { return __uint_as_float(u & 0xffff0000u); }

// Shared-memory union: GEMM staging vs builder scratch (block 0 only uses .b)
union SMU {
    struct { unsigned short sA[128 * GBK]; unsigned short sB[128 * GBK]; } g;   // 32 KB
    struct { int scnt[NNODES]; int psA[256]; int psB[256];
             float sdinv[NNODES]; float fb[NNODES]; } b;                        // 14 KB
};

// ---------------- W1 prep (no BN): Wt[n][k] = bf16(W[k][n]) ; cvec[n] = 0 ------------------------
__global__ __launch_bounds__(256) void wprep_kernel(
    const float* __restrict__ W, unsigned short* __restrict__ Wt,
    float* __restrict__ cvec, int K)
{
    const int n = blockIdx.x, k = threadIdx.x;
    if (k < K) Wt[(size_t)n * K + k] = f2bf(W[(size_t)k * DHID + n]);
    if (k == 0) cvec[n] = 0.0f;
}

// ---------------- fused 64-slot stats reduce + BN-finalize + W prep ------------------------------
// p64: 64 slots x 512 floats (sum | sumsq), accumulated atomically by spmm blocks.
__global__ __launch_bounds__(256) void bnwprep_kernel(
    const float* __restrict__ p64, const float* __restrict__ gamma,
    const float* __restrict__ beta, const float* __restrict__ W,
    unsigned short* __restrict__ Wt, float* __restrict__ cvec)
{
    __shared__ float red[256];
    const int n = blockIdx.x, k = threadIdx.x;
    float s = 0.0f, q = 0.0f;
    #pragma unroll
    for (int p = 0; p < 64; ++p) {
        s += p64[p * 512 + k];
        q += p64[p * 512 + 256 + k];
    }
    const float nn = (float)NTOTAL;
    const float mean = s / nn;
    const float var = q / nn - mean * mean;
    const float sc = gamma[k] * rsqrtf(var + 1e-5f);
    const float sh = beta[k] - mean * sc;
    const float wv = W[(size_t)k * DHID + n];
    Wt[(size_t)n * DHID + k] = f2bf(sc * wv);
    red[k] = sh * wv;
    __syncthreads();
    for (int st = 128; st > 0; st >>= 1) {
        if (k < st) red[k] += red[k + st];
        __syncthreads();
    }
    if (k == 0) cvec[n] = red[0];
}

// ---------------- GEMM-1 (fp32 A, in-kernel cvt) + fused CSR builder (block 0) -------------------
// ecw entries now pack (byte_offset = col*DHID*2, weight) so spmm's inner loop
// needs no per-edge multiply.
__global__ __launch_bounds__(256) void gemm1_kernel(
    const float* __restrict__ x, const unsigned short* __restrict__ Wt,
    unsigned short* __restrict__ C,
    const int* __restrict__ ei, int E,
    int* __restrict__ offs, uint2* __restrict__ ecw,
    float* __restrict__ rowsum)
{
    __shared__ SMU sm;
    const int t = threadIdx.x;

    if (blockIdx.x == 0) {
        // ---------- builder (256 threads, 4 nodes/thread) ----------
        #pragma unroll
        for (int i = 0; i < 4; ++i) sm.b.scnt[t * 4 + i] = 1;
        __syncthreads();
        for (int e = t; e < E; e += 256) atomicAdd(&sm.b.scnt[ei[E + e]], 1);
        __syncthreads();
        int c[4]; int ssum = 0;
        #pragma unroll
        for (int i = 0; i < 4; ++i) { c[i] = sm.b.scnt[t * 4 + i]; ssum += c[i]; }
        sm.b.psA[t] = ssum;
        __syncthreads();
        int* src = sm.b.psA; int* dst = sm.b.psB;
        for (int d = 1; d < 256; d <<= 1) {          // 8 iters (even) -> result in psA
            dst[t] = src[t] + (t >= d ? src[t - d] : 0);
            __syncthreads();
            int* tmp = src; src = dst; dst = tmp;
        }
        int run = src[t] - ssum;                     // exclusive prefix of this 4-node group
        float di[4]; int pos[4];
        #pragma unroll
        for (int i = 0; i < 4; ++i) {
            offs[t * 4 + i] = run;
            di[i] = rsqrtf((float)c[i]);
            sm.b.sdinv[t * 4 + i] = di[i];
            pos[i] = run;
            run += c[i];
        }
        if (t == 255) offs[NNODES] = run;
        __syncthreads();
        #pragma unroll
        for (int i = 0; i < 4; ++i) {                // self loop first; cursor continues after it
            ecw[pos[i]] = make_uint2((unsigned)((t * 4 + i) * DHID * 2),
                                     __float_as_uint(di[i] * di[i]));
            sm.b.scnt[t * 4 + i] = pos[i] + 1;
            sm.b.fb[t * 4 + i] = di[i] * di[i];
        }
        __syncthreads();
        for (int e = t; e < E; e += 256) {
            const int sN = ei[e], dN = ei[E + e];
            const int p = atomicAdd(&sm.b.scnt[dN], 1);
            const float wv = sm.b.sdinv[sN] * sm.b.sdinv[dN];
            ecw[p] = make_uint2((unsigned)(sN * DHID * 2), __float_as_uint(wv));
            atomicAdd(&sm.b.fb[dN], wv);
        }
        __syncthreads();
        #pragma unroll
        for (int i = 0; i < 4; ++i) rowsum[t * 4 + i] = sm.b.fb[t * 4 + i];
        return;
    }

    // ---------- GEMM path ----------
    const int bid = blockIdx.x - 1;
    const int xcd = bid & 7, kk_ = bid >> 3;
    const int m0 = ((kk_ >> 1) * 8 + xcd) * 128;     // n-tile pair of an m-panel shares an XCD
    const int n0 = (kk_ & 1) * 128;
    const int K = FEAT_IN;

    const int w = t >> 6, lane = t & 63;
    const int wr = w >> 1, wc = w & 1;
    const int lr = lane & 15, lk = lane >> 4;
    const int srow = lane >> 3;
    const int seg_src = (lane & 7) ^ srow;           // inverse-swizzled source segment

    f32x4 acc[4][4];
    #pragma unroll
    for (int i = 0; i < 4; ++i)
        #pragma unroll
        for (int j = 0; j < 4; ++j)
            acc[i][j] = (f32x4){0.f, 0.f, 0.f, 0.f};

    const int r = t >> 1, kh = (t & 1) * 32;         // A-staging: row r, k-range [kh, kh+32)
    for (int s = 0; s < 2; ++s) {                    // K=128 -> 2 steps
        if (s > 0) __syncthreads();
        #pragma unroll
        for (int i = 0; i < 4; ++i) {
            const int row = (w * 4 + i) * 8 + srow;
            const unsigned short* gb = Wt + (size_t)(n0 + row) * K + s * GBK + seg_src * 8;
            __builtin_amdgcn_global_load_lds(
                (const __attribute__((address_space(1))) unsigned int*)gb,
                (__attribute__((address_space(3))) unsigned int*)&sm.g.sB[(w * 4 + i) * 512],
                16, 0, 0);
        }
        const float* ga = x + (size_t)(m0 + r) * K + s * GBK + kh;
        #pragma unroll
        for (int j = 0; j < 4; ++j) {
            const float4 v0 = *(const float4*)(ga + j * 8);
            const float4 v1 = *(const float4*)(ga + j * 8 + 4);
            us8 o;
            o[0] = f2bf(v0.x); o[1] = f2bf(v0.y); o[2] = f2bf(v0.z); o[3] = f2bf(v0.w);
            o[4] = f2bf(v1.x); o[5] = f2bf(v1.y); o[6] = f2bf(v1.z); o[7] = f2bf(v1.w);
            const int slot = ((kh >> 3) + j) ^ (r & 7);
            *(us8*)&sm.g.sA[r * 64 + slot * 8] = o;
        }
        __syncthreads();                             // drains B vmcnt + A lds writes
        const char* pa = (const char*)sm.g.sA;
        const char* pb = (const char*)sm.g.sB;
        #pragma unroll
        for (int ks = 0; ks < 2; ++ks) {
            bf16x8 af[4], bfv[4];
            #pragma unroll
            for (int f = 0; f < 4; ++f) {
                const int ra = wr * 64 + f * 16 + lr;
                af[f] = *(const bf16x8*)(pa + ra * 128 + ((ks * 64 + lk * 16) ^ ((ra & 7) << 4)));
                const int rb = wc * 64 + f * 16 + lr;
                bfv[f] = *(const bf16x8*)(pb + rb * 128 + ((ks * 64 + lk * 16) ^ ((rb & 7) << 4)));
            }
            #pragma unroll
            for (int mf = 0; mf < 4; ++mf)
                #pragma unroll
                for (int nf = 0; nf < 4; ++nf)
                    acc[mf][nf] = __builtin_amdgcn_mfma_f32_16x16x32_bf16(
                        af[mf], bfv[nf], acc[mf][nf], 0, 0, 0);
        }
    }

    #pragma unroll
    for (int mf = 0; mf < 4; ++mf) {
        const int rbase = m0 + wr * 64 + mf * 16 + lk * 4;
        #pragma unroll
        for (int nf = 0; nf < 4; ++nf) {
            const int c = n0 + wc * 64 + nf * 16 + lr;
            #pragma unroll
            for (int rr = 0; rr < 4; ++rr)
                C[(size_t)(rbase + rr) * DHID + c] = f2bf(acc[mf][nf][rr]);
        }
    }
}

// ---------------- MFMA GEMM (layers 2/3): C[M][256] = bf16(A @ Wt^T), A bf16 ---------------------
__global__ __launch_bounds__(256) void mgemm_kernel(
    const unsigned short* __restrict__ Ain,
    const unsigned short* __restrict__ Wt,
    unsigned short* __restrict__ C, int K)
{
    __shared__ unsigned short sA[2][128 * GBK];
    __shared__ unsigned short sB[2][128 * GBK];

    const int t = threadIdx.x;
    const int bid = blockIdx.x;
    const int xcd = bid & 7, kk_ = bid >> 3;
    const int m0 = ((kk_ >> 1) * 8 + xcd) * 128;
    const int n0 = (kk_ & 1) * 128;

    const int w = t >> 6, lane = t & 63;
    const int wr = w >> 1, wc = w & 1;
    const int lr = lane & 15, lk = lane >> 4;
    const int srow = lane >> 3;
    const int seg_src = (lane & 7) ^ srow;

    f32x4 acc[4][4];
    #pragma unroll
    for (int i = 0; i < 4; ++i)
        #pragma unroll
        for (int j = 0; j < 4; ++j)
            acc[i][j] = (f32x4){0.f, 0.f, 0.f, 0.f};

    const int nsteps = K >> 6;

    auto stage = [&](int buf, int k0) {
        #pragma unroll
        for (int i = 0; i < 4; ++i) {
            const int row = (w * 4 + i) * 8 + srow;
            const unsigned short* ga = Ain + (size_t)(m0 + row) * K + k0 + seg_src * 8;
            __builtin_amdgcn_global_load_lds(
                (const __attribute__((address_space(1))) unsigned int*)ga,
                (__attribute__((address_space(3))) unsigned int*)&sA[buf][(w * 4 + i) * 512],
                16, 0, 0);
            const unsigned short* gb = Wt + (size_t)(n0 + row) * K + k0 + seg_src * 8;
            __builtin_amdgcn_global_load_lds(
                (const __attribute__((address_space(1))) unsigned int*)gb,
                (__attribute__((address_space(3))) unsigned int*)&sB[buf][(w * 4 + i) * 512],
                16, 0, 0);
        }
    };

    stage(0, 0);
    __syncthreads();
    for (int s = 0; s < nsteps; ++s) {
        if (s + 1 < nsteps) stage((s + 1) & 1, (s + 1) * GBK);
        const char* pa = (const char*)sA[s & 1];
        const char* pb = (const char*)sB[s & 1];
        #pragma unroll
        for (int ks = 0; ks < 2; ++ks) {
            bf16x8 af[4], bfv[4];
            #pragma unroll
            for (int f = 0; f < 4; ++f) {
                const int ra = wr * 64 + f * 16 + lr;
                af[f] = *(const bf16x8*)(pa + ra * 128 + ((ks * 64 + lk * 16) ^ ((ra & 7) << 4)));
                const int rb = wc * 64 + f * 16 + lr;
                bfv[f] = *(const bf16x8*)(pb + rb * 128 + ((ks * 64 + lk * 16) ^ ((rb & 7) << 4)));
            }
            #pragma unroll
            for (int mf = 0; mf < 4; ++mf)
                #pragma unroll
                for (int nf = 0; nf < 4; ++nf)
                    acc[mf][nf] = __builtin_amdgcn_mfma_f32_16x16x32_bf16(
                        af[mf], bfv[nf], acc[mf][nf], 0, 0, 0);
        }
        __syncthreads();
    }

    #pragma unroll
    for (int mf = 0; mf < 4; ++mf) {
        const int rbase = m0 + wr * 64 + mf * 16 + lk * 4;
        #pragma unroll
        for (int nf = 0; nf < 4; ++nf) {
            const int c = n0 + wc * 64 + nf * 16 + lr;
            #pragma unroll
            for (int rr = 0; rr < 4; ++rr)
                C[(size_t)(rbase + rr) * DHID + c] = f2bf(acc[mf][nf][rr]);
        }
    }
}

// ---------------- SpMM: h = relu(Anorm @ hw + rowsum*c + b), 32 nodes/block, 512 threads ---------
// Lane l owns features 4l..4l+3 (8B uint2 loads); wave w owns 4 of the block's 32 nodes.
// Edge metadata packed (byte-offset, weight): inner loop is one add + gather per edge.
// rowsum staged in LDS. XCD-affine graph mapping keeps each graph's hw slab in one L2.
// Stats: per-block sums atomically accumulated into 64-slot p64.
#define NB 32
#define ECAPB 512

template<bool STATS, bool OUTF32>
__global__ __launch_bounds__(512) void spmm_kernel(
    const unsigned short* __restrict__ hw, const float* __restrict__ bias,
    const float* __restrict__ rowsum, const float* __restrict__ cvec,
    void* __restrict__ hout, float* __restrict__ p64,
    const int* __restrict__ offs, const uint2* __restrict__ ecw)
{
    __shared__ uint2 sew[ECAPB];
    __shared__ int soff[NB + 1];
    __shared__ float srs[NB];
    __shared__ float spartS[8][256];
    __shared__ float spartQ[8][256];

    const int b = blockIdx.x;                 // 4096 blocks
    const int xcd = b & 7;
    const int idx = b >> 3;
    const int g  = (idx >> 5) * 8 + xcd;      // all 32 blocks of graph g on one XCD
    const int nb = (idx & 31) * NB;
    const int t = threadIdx.x;
    const int w = t >> 6, l = t & 63;
    const int f0 = l * 4;
    const char* __restrict__ hb =
        (const char*)(hw + (size_t)g * NNODES * DHID) + (size_t)f0 * 2;

    if (t <= NB) soff[t] = offs[nb + t];
    if (t < NB)  srs[t] = rowsum[nb + t];
    __syncthreads();
    const int base = soff[0];
    const int tot = soff[NB] - base;          // ~290, cap 512
    for (int e = t; e < tot; e += 512) sew[e] = ecw[base + e];
    __syncthreads();

    const float4 bv = *(const float4*)(bias + f0);
    const float4 cv = *(const float4*)(cvec + f0);
    float ps0=0, ps1=0, ps2=0, ps3=0, pq0=0, pq1=0, pq2=0, pq3=0;

    #pragma unroll 1
    for (int j = 0; j < 4; ++j) {
        const int i = w * 4 + j;
        const int s = soff[i] - base, e = soff[i + 1] - base;
        const float rs = srs[i];
        float a0=0, a1=0, a2=0, a3=0;
        int k = s;
        #pragma unroll 1
        for (; k + 4 <= e; k += 4) {
            const uint2 p0 = sew[k+0], p1 = sew[k+1], p2 = sew[k+2], p3 = sew[k+3];
            const uint2 u0 = *(const uint2*)(hb + p0.x);
            const uint2 u1 = *(const uint2*)(hb + p1.x);
            const uint2 u2 = *(const uint2*)(hb + p2.x);
            const uint2 u3 = *(const uint2*)(hb + p3.x);
            const float w0 = __uint_as_float(p0.y), w1 = __uint_as_float(p1.y);
            const float w2 = __uint_as_float(p2.y), w3 = __uint_as_float(p3.y);
            a0 = fmaf(w0, blo(u0.x), a0); a1 = fmaf(w0, bhi(u0.x), a1);
            a2 = fmaf(w0, blo(u0.y), a2); a3 = fmaf(w0, bhi(u0.y), a3);
            a0 = fmaf(w1, blo(u1.x), a0); a1 = fmaf(w1, bhi(u1.x), a1);
            a2 = fmaf(w1, blo(u1.y), a2); a3 = fmaf(w1, bhi(u1.y), a3);
            a0 = fmaf(w2, blo(u2.x), a0); a1 = fmaf(w2, bhi(u2.x), a1);
            a2 = fmaf(w2, blo(u2.y), a2); a3 = fmaf(w2, bhi(u2.y), a3);
            a0 = fmaf(w3, blo(u3.x), a0); a1 = fmaf(w3, bhi(u3.x), a1);
            a2 = fmaf(w3, blo(u3.y), a2); a3 = fmaf(w3, bhi(u3.y), a3);
        }
        #pragma unroll 1
        for (; k < e; ++k) {
            const uint2 p = sew[k];
            const uint2 u = *(const uint2*)(hb + p.x);
            const float wk = __uint_as_float(p.y);
            a0 = fmaf(wk, blo(u.x), a0); a1 = fmaf(wk, bhi(u.x), a1);
            a2 = fmaf(wk, blo(u.y), a2); a3 = fmaf(wk, bhi(u.y), a3);
        }

        const float v0 = fmaxf(fmaf(rs, cv.x, a0) + bv.x, 0.0f);
        const float v1 = fmaxf(fmaf(rs, cv.y, a1) + bv.y, 0.0f);
        const float v2 = fmaxf(fmaf(rs, cv.z, a2) + bv.z, 0.0f);
        const float v3 = fmaxf(fmaf(rs, cv.w, a3) + bv.w, 0.0f);
        const size_t orow = (size_t)g * NNODES + nb + i;
        if (OUTF32) {
            *(float4*)((float*)hout + orow * DHID + f0) = make_float4(v0, v1, v2, v3);
        } else {
            us4 o; o[0] = f2bf(v0); o[1] = f2bf(v1); o[2] = f2bf(v2); o[3] = f2bf(v3);
            *(us4*)((unsigned short*)hout + orow * DHID + f0) = o;
        }
        if (STATS) {
            ps0 += v0; ps1 += v1; ps2 += v2; ps3 += v3;
            pq0 += v0*v0; pq1 += v1*v1; pq2 += v2*v2; pq3 += v3*v3;
        }
    }

    if (STATS) {
        spartS[w][f0+0] = ps0; spartS[w][f0+1] = ps1; spartS[w][f0+2] = ps2; spartS[w][f0+3] = ps3;
        spartQ[w][f0+0] = pq0; spartQ[w][f0+1] = pq1; spartQ[w][f0+2] = pq2; spartQ[w][f0+3] = pq3;
        __syncthreads();
        if (t < 256) {
            float ss = 0.0f, sq = 0.0f;
            #pragma unroll
            for (int p = 0; p < 8; ++p) { ss += spartS[p][t]; sq += spartQ[p][t]; }
            float* slot = p64 + (size_t)(b & 63) * 512;
            atomicAdd(&slot[t], ss);
            atomicAdd(&slot[256 + t], sq);
        }
    }
}

// ---------------- launch -------------------------------------------------------------------------
extern "C" void kernel_launch(void* const* d_in, const int* in_sizes, int n_in,
                              void* d_out, int out_size, void* d_ws, size_t ws_size,
                              hipStream_t stream)
{
    const float* x      = (const float*)d_in[0];
    const int*   ei     = (const int*)d_in[1];
    const float* W1     = (const float*)d_in[3];
    const float* b1     = (const float*)d_in[4];
    const float* W2     = (const float*)d_in[5];
    const float* b2     = (const float*)d_in[6];
    const float* W3     = (const float*)d_in[7];
    const float* b3     = (const float*)d_in[8];
    const float* gamma1 = (const float*)d_in[9];
    const float* beta1  = (const float*)d_in[10];
    const float* gamma2 = (const float*)d_in[11];
    const float* beta2  = (const float*)d_in[12];
    float* out = (float*)d_out;

    const int E = in_sizes[1] / 2;   // 8192

    // workspace layout (total ~135 MB + meta)
    char* w = (char*)d_ws;
    unsigned short* hA = (unsigned short*)w;                 // h bf16 (67 MB)
    unsigned short* hw = (unsigned short*)(w + 67108864);    // 67 MB
    char* meta = w + 134217728;
    float* p64a   = (float*)meta;          meta += 64 * 512 * 4;   // layer-1 stats slots
    float* p64b   = (float*)meta;          meta += 64 * 512 * 4;   // layer-2 stats slots
    int*   offs   = (int*)meta;            meta += 4352;
    uint2* ecw    = (uint2*)meta;          meta += ECAP * 8;
    float* rowsum = (float*)meta;          meta += NNODES * 4;
    float* cvec1  = (float*)meta;          meta += 256 * 4;
    float* cvec2  = (float*)meta;          meta += 256 * 4;
    float* cvec3  = (float*)meta;          meta += 256 * 4;
    unsigned short* wt1 = (unsigned short*)meta;  meta += 256 * 128 * 2;
    unsigned short* wt2 = (unsigned short*)meta;  meta += 256 * 256 * 2;
    unsigned short* wt3 = (unsigned short*)meta;  meta += 256 * 256 * 2;

    const int GG = 2048;                 // GEMM blocks (pairing swizzle decoded in-kernel)
    const int P  = NTOTAL / NB;          // 4096 spmm blocks

    hipMemsetAsync(p64a, 0, 2 * 64 * 512 * 4, stream);   // zero both stats slabs (128 KB)
    wprep_kernel<<<DHID, 256, 0, stream>>>(W1, wt1, cvec1, FEAT_IN);

    // Layer 1: GEMM (x fp32 converted in-kernel) + CSR builder fused as block 0
    gemm1_kernel<<<GG + 1, 256, 0, stream>>>(x, wt1, hw, ei, E, offs, ecw, rowsum);
    spmm_kernel<true, false><<<P, 512, 0, stream>>>(hw, b1, rowsum, cvec1, hA, p64a, offs, ecw);
    bnwprep_kernel<<<DHID, 256, 0, stream>>>(p64a, gamma1, beta1, W2, wt2, cvec2);

    // Layer 2
    mgemm_kernel<<<GG, 256, 0, stream>>>(hA, wt2, hw, DHID);
    spmm_kernel<true, false><<<P, 512, 0, stream>>>(hw, b2, rowsum, cvec2, hA, p64b, offs, ecw);
    bnwprep_kernel<<<DHID, 256, 0, stream>>>(p64b, gamma2, beta2, W3, wt3, cvec3);

    // Layer 3 (fp32 output, no stats)
    mgemm_kernel<<<GG, 256, 0, stream>>>(hA, wt3, hw, DHID);
    spmm_kernel<false, true><<<P, 512, 0, stream>>>(hw, b3, rowsum, cvec3, out, nullptr, offs, ecw);
}

// Round 15
// 283.827 us; speedup vs baseline: 1.2765x; 1.0203x over previous
//
#include <hip/hip_runtime.h>

// Problem constants (fixed instance):
//   B=128 graphs, N=1024 nodes/graph, F=128 in-feats, D=256 hidden, E=8192 edges/graph
#define NNODES   1024
#define NGRAPH   128
#define NTOTAL   (NNODES * NGRAPH)   // 131072
#define FEAT_IN  128
#define DHID     256
#define ECAP     (16384 + NNODES)    // CSR capacity
#define GBK      64

typedef __attribute__((ext_vector_type(8))) short bf16x8;
typedef __attribute__((ext_vector_type(4))) float f32x4;
typedef __attribute__((ext_vector_type(4))) unsigned short us4;
typedef __attribute__((ext_vector_type(8))) unsigned short us8;

__device__ __forceinline__ unsigned short f2bf(float f) {
    unsigned int u = __float_as_uint(f);
    u += 0x7fffu + ((u >> 16) & 1u);           // RNE
    return (unsigned short)(u >> 16);
}
__device__ __forceinline__ float blo(unsigned int u) { return __uint_as_float(u << 16); }
__device__ __forceinline__ float bhi(unsigned int u) { return __uint_as_float(u & 0xffff0000u); }

// GEMM block decode, shared by all GEMM kernels.
// XCD-affinity matched to spmm: graph g lives on XCD g&7 for its hw-write,
// gather-read, h-write, and next-layer A-read (producer/consumer L2 locality).
// bid in [0,2048): xcd=bid&7; j=bid>>3; nt=j&1; pj=j>>1;
//   graph=(pj>>3)*8+xcd; panel=pj&7; m0=(graph*8+panel)*128; n0=nt*128.
// n-tile pair (nt=0,1) of a panel stays on one XCD -> A-panel L2 reuse kept.
__device__ __forceinline__ void gemm_decode(int bid, int& m0, int& n0) {
    const int xcd = bid & 7, j = bid >> 3;
    const int nt = j & 1, pj = j >> 1;
    const int graph = (pj >> 3) * 8 + xcd;
    const int panel = pj & 7;
    m0 = (graph * 8 + panel) * 128;
    n0 = nt * 128;
}

// Shared-memory union: GEMM staging vs builder scratch (block 0 only uses .b)
union SMU {
    struct { unsigned short sA[128 * GBK]; unsigned short sB[128 * GBK]; } g;   // 32 KB
    struct { int scnt[NNODES]; int psA[256]; int psB[256];
             float sdinv[NNODES]; float fb[NNODES]; } b;                        // 14 KB
};

// ---------------- W1 prep (no BN): Wt[n][k] = bf16(W[k][n]) ; cvec[n] = 0 ; zero p64 -------------
__global__ __launch_bounds__(256) void wprep_kernel(
    const float* __restrict__ W, unsigned short* __restrict__ Wt,
    float* __restrict__ cvec, int K, float* __restrict__ p64 /* 65536 floats */)
{
    const int n = blockIdx.x, k = threadIdx.x;
    if (k < K) Wt[(size_t)n * K + k] = f2bf(W[(size_t)k * DHID + n]);
    if (k == 0) cvec[n] = 0.0f;
    p64[n * 256 + k] = 0.0f;              // 256 blocks x 256 threads = both stats slabs
}

// ---------------- fused 64-slot stats reduce + BN-finalize + W prep ------------------------------
__global__ __launch_bounds__(256) void bnwprep_kernel(
    const float* __restrict__ p64, const float* __restrict__ gamma,
    const float* __restrict__ beta, const float* __restrict__ W,
    unsigned short* __restrict__ Wt, float* __restrict__ cvec)
{
    __shared__ float red[256];
    const int n = blockIdx.x, k = threadIdx.x;
    float s = 0.0f, q = 0.0f;
    #pragma unroll
    for (int p = 0; p < 64; ++p) {
        s += p64[p * 512 + k];
        q += p64[p * 512 + 256 + k];
    }
    const float nn = (float)NTOTAL;
    const float mean = s / nn;
    const float var = q / nn - mean * mean;
    const float sc = gamma[k] * rsqrtf(var + 1e-5f);
    const float sh = beta[k] - mean * sc;
    const float wv = W[(size_t)k * DHID + n];
    Wt[(size_t)n * DHID + k] = f2bf(sc * wv);
    red[k] = sh * wv;
    __syncthreads();
    for (int st = 128; st > 0; st >>= 1) {
        if (k < st) red[k] += red[k + st];
        __syncthreads();
    }
    if (k == 0) cvec[n] = red[0];
}

// ---------------- GEMM-1 (fp32 A, in-kernel cvt) + fused CSR builder (block 0) -------------------
__global__ __launch_bounds__(256) void gemm1_kernel(
    const float* __restrict__ x, const unsigned short* __restrict__ Wt,
    unsigned short* __restrict__ C,
    const int* __restrict__ ei, int E,
    int* __restrict__ offs, uint2* __restrict__ ecw,
    float* __restrict__ rowsum)
{
    __shared__ SMU sm;
    const int t = threadIdx.x;

    if (blockIdx.x == 0) {
        // ---------- builder (256 threads, 4 nodes/thread) ----------
        #pragma unroll
        for (int i = 0; i < 4; ++i) sm.b.scnt[t * 4 + i] = 1;
        __syncthreads();
        for (int e = t; e < E; e += 256) atomicAdd(&sm.b.scnt[ei[E + e]], 1);
        __syncthreads();
        int c[4]; int ssum = 0;
        #pragma unroll
        for (int i = 0; i < 4; ++i) { c[i] = sm.b.scnt[t * 4 + i]; ssum += c[i]; }
        sm.b.psA[t] = ssum;
        __syncthreads();
        int* src = sm.b.psA; int* dst = sm.b.psB;
        for (int d = 1; d < 256; d <<= 1) {          // 8 iters (even) -> result in psA
            dst[t] = src[t] + (t >= d ? src[t - d] : 0);
            __syncthreads();
            int* tmp = src; src = dst; dst = tmp;
        }
        int run = src[t] - ssum;                     // exclusive prefix of this 4-node group
        float di[4]; int pos[4];
        #pragma unroll
        for (int i = 0; i < 4; ++i) {
            offs[t * 4 + i] = run;
            di[i] = rsqrtf((float)c[i]);
            sm.b.sdinv[t * 4 + i] = di[i];
            pos[i] = run;
            run += c[i];
        }
        if (t == 255) offs[NNODES] = run;
        __syncthreads();
        #pragma unroll
        for (int i = 0; i < 4; ++i) {                // self loop first; cursor continues after it
            ecw[pos[i]] = make_uint2((unsigned)((t * 4 + i) * DHID * 2),
                                     __float_as_uint(di[i] * di[i]));
            sm.b.scnt[t * 4 + i] = pos[i] + 1;
            sm.b.fb[t * 4 + i] = di[i] * di[i];
        }
        __syncthreads();
        for (int e = t; e < E; e += 256) {
            const int sN = ei[e], dN = ei[E + e];
            const int p = atomicAdd(&sm.b.scnt[dN], 1);
            const float wv = sm.b.sdinv[sN] * sm.b.sdinv[dN];
            ecw[p] = make_uint2((unsigned)(sN * DHID * 2), __float_as_uint(wv));
            atomicAdd(&sm.b.fb[dN], wv);
        }
        __syncthreads();
        #pragma unroll
        for (int i = 0; i < 4; ++i) rowsum[t * 4 + i] = sm.b.fb[t * 4 + i];
        return;
    }

    // ---------- GEMM path ----------
    int m0, n0;
    gemm_decode(blockIdx.x - 1, m0, n0);
    const int K = FEAT_IN;

    const int w = t >> 6, lane = t & 63;
    const int wr = w >> 1, wc = w & 1;
    const int lr = lane & 15, lk = lane >> 4;
    const int srow = lane >> 3;
    const int seg_src = (lane & 7) ^ srow;           // inverse-swizzled source segment

    f32x4 acc[4][4];
    #pragma unroll
    for (int i = 0; i < 4; ++i)
        #pragma unroll
        for (int j = 0; j < 4; ++j)
            acc[i][j] = (f32x4){0.f, 0.f, 0.f, 0.f};

    const int r = t >> 1, kh = (t & 1) * 32;         // A-staging: row r, k-range [kh, kh+32)
    for (int s = 0; s < 2; ++s) {                    // K=128 -> 2 steps
        if (s > 0) __syncthreads();
        #pragma unroll
        for (int i = 0; i < 4; ++i) {
            const int row = (w * 4 + i) * 8 + srow;
            const unsigned short* gb = Wt + (size_t)(n0 + row) * K + s * GBK + seg_src * 8;
            __builtin_amdgcn_global_load_lds(
                (const __attribute__((address_space(1))) unsigned int*)gb,
                (__attribute__((address_space(3))) unsigned int*)&sm.g.sB[(w * 4 + i) * 512],
                16, 0, 0);
        }
        const float* ga = x + (size_t)(m0 + r) * K + s * GBK + kh;
        #pragma unroll
        for (int j = 0; j < 4; ++j) {
            const float4 v0 = *(const float4*)(ga + j * 8);
            const float4 v1 = *(const float4*)(ga + j * 8 + 4);
            us8 o;
            o[0] = f2bf(v0.x); o[1] = f2bf(v0.y); o[2] = f2bf(v0.z); o[3] = f2bf(v0.w);
            o[4] = f2bf(v1.x); o[5] = f2bf(v1.y); o[6] = f2bf(v1.z); o[7] = f2bf(v1.w);
            const int slot = ((kh >> 3) + j) ^ (r & 7);
            *(us8*)&sm.g.sA[r * 64 + slot * 8] = o;
        }
        __syncthreads();                             // drains B vmcnt + A lds writes
        const char* pa = (const char*)sm.g.sA;
        const char* pb = (const char*)sm.g.sB;
        #pragma unroll
        for (int ks = 0; ks < 2; ++ks) {
            bf16x8 af[4], bfv[4];
            #pragma unroll
            for (int f = 0; f < 4; ++f) {
                const int ra = wr * 64 + f * 16 + lr;
                af[f] = *(const bf16x8*)(pa + ra * 128 + ((ks * 64 + lk * 16) ^ ((ra & 7) << 4)));
                const int rb = wc * 64 + f * 16 + lr;
                bfv[f] = *(const bf16x8*)(pb + rb * 128 + ((ks * 64 + lk * 16) ^ ((rb & 7) << 4)));
            }
            #pragma unroll
            for (int mf = 0; mf < 4; ++mf)
                #pragma unroll
                for (int nf = 0; nf < 4; ++nf)
                    acc[mf][nf] = __builtin_amdgcn_mfma_f32_16x16x32_bf16(
                        af[mf], bfv[nf], acc[mf][nf], 0, 0, 0);
        }
    }

    #pragma unroll
    for (int mf = 0; mf < 4; ++mf) {
        const int rbase = m0 + wr * 64 + mf * 16 + lk * 4;
        #pragma unroll
        for (int nf = 0; nf < 4; ++nf) {
            const int c = n0 + wc * 64 + nf * 16 + lr;
            #pragma unroll
            for (int rr = 0; rr < 4; ++rr)
                C[(size_t)(rbase + rr) * DHID + c] = f2bf(acc[mf][nf][rr]);
        }
    }
}

// ---------------- MFMA GEMM (layers 2/3): C[M][256] = bf16(A @ Wt^T), A bf16 ---------------------
__global__ __launch_bounds__(256) void mgemm_kernel(
    const unsigned short* __restrict__ Ain,
    const unsigned short* __restrict__ Wt,
    unsigned short* __restrict__ C, int K)
{
    __shared__ unsigned short sA[2][128 * GBK];
    __shared__ unsigned short sB[2][128 * GBK];

    const int t = threadIdx.x;
    int m0, n0;
    gemm_decode(blockIdx.x, m0, n0);

    const int w = t >> 6, lane = t & 63;
    const int wr = w >> 1, wc = w & 1;
    const int lr = lane & 15, lk = lane >> 4;
    const int srow = lane >> 3;
    const int seg_src = (lane & 7) ^ srow;

    f32x4 acc[4][4];
    #pragma unroll
    for (int i = 0; i < 4; ++i)
        #pragma unroll
        for (int j = 0; j < 4; ++j)
            acc[i][j] = (f32x4){0.f, 0.f, 0.f, 0.f};

    const int nsteps = K >> 6;

    auto stage = [&](int buf, int k0) {
        #pragma unroll
        for (int i = 0; i < 4; ++i) {
            const int row = (w * 4 + i) * 8 + srow;
            const unsigned short* ga = Ain + (size_t)(m0 + row) * K + k0 + seg_src * 8;
            __builtin_amdgcn_global_load_lds(
                (const __attribute__((address_space(1))) unsigned int*)ga,
                (__attribute__((address_space(3))) unsigned int*)&sA[buf][(w * 4 + i) * 512],
                16, 0, 0);
            const unsigned short* gb = Wt + (size_t)(n0 + row) * K + k0 + seg_src * 8;
            __builtin_amdgcn_global_load_lds(
                (const __attribute__((address_space(1))) unsigned int*)gb,
                (__attribute__((address_space(3))) unsigned int*)&sB[buf][(w * 4 + i) * 512],
                16, 0, 0);
        }
    };

    stage(0, 0);
    __syncthreads();
    for (int s = 0; s < nsteps; ++s) {
        if (s + 1 < nsteps) stage((s + 1) & 1, (s + 1) * GBK);
        const char* pa = (const char*)sA[s & 1];
        const char* pb = (const char*)sB[s & 1];
        #pragma unroll
        for (int ks = 0; ks < 2; ++ks) {
            bf16x8 af[4], bfv[4];
            #pragma unroll
            for (int f = 0; f < 4; ++f) {
                const int ra = wr * 64 + f * 16 + lr;
                af[f] = *(const bf16x8*)(pa + ra * 128 + ((ks * 64 + lk * 16) ^ ((ra & 7) << 4)));
                const int rb = wc * 64 + f * 16 + lr;
                bfv[f] = *(const bf16x8*)(pb + rb * 128 + ((ks * 64 + lk * 16) ^ ((rb & 7) << 4)));
            }
            #pragma unroll
            for (int mf = 0; mf < 4; ++mf)
                #pragma unroll
                for (int nf = 0; nf < 4; ++nf)
                    acc[mf][nf] = __builtin_amdgcn_mfma_f32_16x16x32_bf16(
                        af[mf], bfv[nf], acc[mf][nf], 0, 0, 0);
        }
        __syncthreads();
    }

    #pragma unroll
    for (int mf = 0; mf < 4; ++mf) {
        const int rbase = m0 + wr * 64 + mf * 16 + lk * 4;
        #pragma unroll
        for (int nf = 0; nf < 4; ++nf) {
            const int c = n0 + wc * 64 + nf * 16 + lr;
            #pragma unroll
            for (int rr = 0; rr < 4; ++rr)
                C[(size_t)(rbase + rr) * DHID + c] = f2bf(acc[mf][nf][rr]);
        }
    }
}

// ---------------- SpMM: h = relu(Anorm @ hw + rowsum*c + b), 32 nodes/block, 512 threads ---------
// Lane l owns features 4l..4l+3 (8B uint2 loads); wave w owns 4 of the block's 32 nodes.
// Edge metadata packed (byte-offset, weight): inner loop is one add + gather per edge.
// rowsum staged in LDS. XCD-affine graph mapping (g&7) matches the GEMM decode,
// so hw gathers and h writes stay in one XCD's L2 across kernels.
// Stats: per-block sums atomically accumulated into 64-slot p64.
#define NB 32
#define ECAPB 512

template<bool STATS, bool OUTF32>
__global__ __launch_bounds__(512) void spmm_kernel(
    const unsigned short* __restrict__ hw, const float* __restrict__ bias,
    const float* __restrict__ rowsum, const float* __restrict__ cvec,
    void* __restrict__ hout, float* __restrict__ p64,
    const int* __restrict__ offs, const uint2* __restrict__ ecw)
{
    __shared__ uint2 sew[ECAPB];
    __shared__ int soff[NB + 1];
    __shared__ float srs[NB];
    __shared__ float spartS[8][256];
    __shared__ float spartQ[8][256];

    const int b = blockIdx.x;                 // 4096 blocks
    const int xcd = b & 7;
    const int idx = b >> 3;
    const int g  = (idx >> 5) * 8 + xcd;      // all 32 blocks of graph g on one XCD
    const int nb = (idx & 31) * NB;
    const int t = threadIdx.x;
    const int w = t >> 6, l = t & 63;
    const int f0 = l * 4;
    const char* __restrict__ hb =
        (const char*)(hw + (size_t)g * NNODES * DHID) + (size_t)f0 * 2;

    if (t <= NB) soff[t] = offs[nb + t];
    if (t < NB)  srs[t] = rowsum[nb + t];
    __syncthreads();
    const int base = soff[0];
    const int tot = soff[NB] - base;          // ~290, cap 512
    for (int e = t; e < tot; e += 512) sew[e] = ecw[base + e];
    __syncthreads();

    const float4 bv = *(const float4*)(bias + f0);
    const float4 cv = *(const float4*)(cvec + f0);
    float ps0=0, ps1=0, ps2=0, ps3=0, pq0=0, pq1=0, pq2=0, pq3=0;

    #pragma unroll 1
    for (int j = 0; j < 4; ++j) {
        const int i = w * 4 + j;
        const int s = soff[i] - base, e = soff[i + 1] - base;
        const float rs = srs[i];
        float a0=0, a1=0, a2=0, a3=0;
        int k = s;
        #pragma unroll 1
        for (; k + 4 <= e; k += 4) {
            const uint2 p0 = sew[k+0], p1 = sew[k+1], p2 = sew[k+2], p3 = sew[k+3];
            const uint2 u0 = *(const uint2*)(hb + p0.x);
            const uint2 u1 = *(const uint2*)(hb + p1.x);
            const uint2 u2 = *(const uint2*)(hb + p2.x);
            const uint2 u3 = *(const uint2*)(hb + p3.x);
            const float w0 = __uint_as_float(p0.y), w1 = __uint_as_float(p1.y);
            const float w2 = __uint_as_float(p2.y), w3 = __uint_as_float(p3.y);
            a0 = fmaf(w0, blo(u0.x), a0); a1 = fmaf(w0, bhi(u0.x), a1);
            a2 = fmaf(w0, blo(u0.y), a2); a3 = fmaf(w0, bhi(u0.y), a3);
            a0 = fmaf(w1, blo(u1.x), a0); a1 = fmaf(w1, bhi(u1.x), a1);
            a2 = fmaf(w1, blo(u1.y), a2); a3 = fmaf(w1, bhi(u1.y), a3);
            a0 = fmaf(w2, blo(u2.x), a0); a1 = fmaf(w2, bhi(u2.x), a1);
            a2 = fmaf(w2, blo(u2.y), a2); a3 = fmaf(w2, bhi(u2.y), a3);
            a0 = fmaf(w3, blo(u3.x), a0); a1 = fmaf(w3, bhi(u3.x), a1);
            a2 = fmaf(w3, blo(u3.y), a2); a3 = fmaf(w3, bhi(u3.y), a3);
        }
        #pragma unroll 1
        for (; k < e; ++k) {
            const uint2 p = sew[k];
            const uint2 u = *(const uint2*)(hb + p.x);
            const float wk = __uint_as_float(p.y);
            a0 = fmaf(wk, blo(u.x), a0); a1 = fmaf(wk, bhi(u.x), a1);
            a2 = fmaf(wk, blo(u.y), a2); a3 = fmaf(wk, bhi(u.y), a3);
        }

        const float v0 = fmaxf(fmaf(rs, cv.x, a0) + bv.x, 0.0f);
        const float v1 = fmaxf(fmaf(rs, cv.y, a1) + bv.y, 0.0f);
        const float v2 = fmaxf(fmaf(rs, cv.z, a2) + bv.z, 0.0f);
        const float v3 = fmaxf(fmaf(rs, cv.w, a3) + bv.w, 0.0f);
        const size_t orow = (size_t)g * NNODES + nb + i;
        if (OUTF32) {
            *(float4*)((float*)hout + orow * DHID + f0) = make_float4(v0, v1, v2, v3);
        } else {
            us4 o; o[0] = f2bf(v0); o[1] = f2bf(v1); o[2] = f2bf(v2); o[3] = f2bf(v3);
            *(us4*)((unsigned short*)hout + orow * DHID + f0) = o;
        }
        if (STATS) {
            ps0 += v0; ps1 += v1; ps2 += v2; ps3 += v3;
            pq0 += v0*v0; pq1 += v1*v1; pq2 += v2*v2; pq3 += v3*v3;
        }
    }

    if (STATS) {
        spartS[w][f0+0] = ps0; spartS[w][f0+1] = ps1; spartS[w][f0+2] = ps2; spartS[w][f0+3] = ps3;
        spartQ[w][f0+0] = pq0; spartQ[w][f0+1] = pq1; spartQ[w][f0+2] = pq2; spartQ[w][f0+3] = pq3;
        __syncthreads();
        if (t < 256) {
            float ss = 0.0f, sq = 0.0f;
            #pragma unroll
            for (int p = 0; p < 8; ++p) { ss += spartS[p][t]; sq += spartQ[p][t]; }
            float* slot = p64 + (size_t)(b & 63) * 512;
            atomicAdd(&slot[t], ss);
            atomicAdd(&slot[256 + t], sq);
        }
    }
}

// ---------------- launch -------------------------------------------------------------------------
extern "C" void kernel_launch(void* const* d_in, const int* in_sizes, int n_in,
                              void* d_out, int out_size, void* d_ws, size_t ws_size,
                              hipStream_t stream)
{
    const float* x      = (const float*)d_in[0];
    const int*   ei     = (const int*)d_in[1];
    const float* W1     = (const float*)d_in[3];
    const float* b1     = (const float*)d_in[4];
    const float* W2     = (const float*)d_in[5];
    const float* b2     = (const float*)d_in[6];
    const float* W3     = (const float*)d_in[7];
    const float* b3     = (const float*)d_in[8];
    const float* gamma1 = (const float*)d_in[9];
    const float* beta1  = (const float*)d_in[10];
    const float* gamma2 = (const float*)d_in[11];
    const float* beta2  = (const float*)d_in[12];
    float* out = (float*)d_out;

    const int E = in_sizes[1] / 2;   // 8192

    // workspace layout (total ~135 MB + meta)
    char* w = (char*)d_ws;
    unsigned short* hA = (unsigned short*)w;                 // h bf16 (67 MB)
    unsigned short* hw = (unsigned short*)(w + 67108864);    // 67 MB
    char* meta = w + 134217728;
    float* p64a   = (float*)meta;          meta += 64 * 512 * 4;   // layer-1 stats slots
    float* p64b   = (float*)meta;          meta += 64 * 512 * 4;   // layer-2 stats slots (contiguous)
    int*   offs   = (int*)meta;            meta += 4352;
    uint2* ecw    = (uint2*)meta;          meta += ECAP * 8;
    float* rowsum = (float*)meta;          meta += NNODES * 4;
    float* cvec1  = (float*)meta;          meta += 256 * 4;
    float* cvec2  = (float*)meta;          meta += 256 * 4;
    float* cvec3  = (float*)meta;          meta += 256 * 4;
    unsigned short* wt1 = (unsigned short*)meta;  meta += 256 * 128 * 2;
    unsigned short* wt2 = (unsigned short*)meta;  meta += 256 * 256 * 2;
    unsigned short* wt3 = (unsigned short*)meta;  meta += 256 * 256 * 2;

    const int GG = 2048;                 // GEMM blocks (XCD-affine decode in-kernel)
    const int P  = NTOTAL / NB;          // 4096 spmm blocks

    wprep_kernel<<<DHID, 256, 0, stream>>>(W1, wt1, cvec1, FEAT_IN, p64a);  // also zeroes p64a+p64b

    // Layer 1: GEMM (x fp32 converted in-kernel) + CSR builder fused as block 0
    gemm1_kernel<<<GG + 1, 256, 0, stream>>>(x, wt1, hw, ei, E, offs, ecw, rowsum);
    spmm_kernel<true, false><<<P, 512, 0, stream>>>(hw, b1, rowsum, cvec1, hA, p64a, offs, ecw);
    bnwprep_kernel<<<DHID, 256, 0, stream>>>(p64a, gamma1, beta1, W2, wt2, cvec2);

    // Layer 2
    mgemm_kernel<<<GG, 256, 0, stream>>>(hA, wt2, hw, DHID);
    spmm_kernel<true, false><<<P, 512, 0, stream>>>(hw, b2, rowsum, cvec2, hA, p64b, offs, ecw);
    bnwprep_kernel<<<DHID, 256, 0, stream>>>(p64b, gamma2, beta2, W3, wt3, cvec3);

    // Layer 3 (fp32 output, no stats)
    mgemm_kernel<<<GG, 256, 0, stream>>>(hA, wt3, hw, DHID);
    spmm_kernel<false, true><<<P, 512, 0, stream>>>(hw, b3, rowsum, cvec3, out, nullptr, offs, ecw);
}

// Round 16
// 277.674 us; speedup vs baseline: 1.3047x; 1.0222x over previous
//
#include <hip/hip_runtime.h>

// Problem constants (fixed instance):
//   B=128 graphs, N=1024 nodes/graph, F=128 in-feats, D=256 hidden, E=8192 edges/graph
#define NNODES   1024
#define NGRAPH   128
#define NTOTAL   (NNODES * NGRAPH)   // 131072
#define FEAT_IN  128
#define DHID     256
#define ECAP     (16384 + NNODES)    // CSR capacity
#define GBK      64

typedef __attribute__((ext_vector_type(8))) short bf16x8;
typedef __attribute__((ext_vector_type(4))) float f32x4;
typedef __attribute__((ext_vector_type(4))) unsigned short us4;
typedef __attribute__((ext_vector_type(8))) unsigned short us8;

__device__ __forceinline__ unsigned short f2bf(float f) {
    unsigned int u = __float_as_uint(f);
    u += 0x7fffu + ((u >> 16) & 1u);           // RNE
    return (unsigned short)(u >> 16);
}
__device__ __forceinline__ float blo(unsigned int u) { return __uint_as_float(u << 16); }
__device__ __forceinline__ float bhi(unsigned int u) { return __uint_as_float(u & 0xffff0000u); }

// GEMM block decode, shared by all GEMM kernels.
// XCD-affinity matched to spmm: graph g lives on XCD g&7 for its hw-write,
// gather-read, h-write, and next-layer A-read (producer/consumer L2 locality).
__device__ __forceinline__ void gemm_decode(int bid, int& m0, int& n0) {
    const int xcd = bid & 7, j = bid >> 3;
    const int nt = j & 1, pj = j >> 1;
    const int graph = (pj >> 3) * 8 + xcd;
    const int panel = pj & 7;
    m0 = (graph * 8 + panel) * 128;
    n0 = nt * 128;
}

// Shared-memory union: GEMM staging vs builder scratch (block 0 only uses .b)
union SMU {
    struct { unsigned short sA[128 * GBK]; unsigned short sB[128 * GBK]; } g;   // 32 KB
    struct { int scnt[NNODES]; int psA[256]; int psB[256];
             float sdinv[NNODES]; float fb[NNODES]; } b;                        // 14 KB
};

// ---------------- W1 prep (no BN): Wt[n][k] = bf16(W[k][n]) ; cvec[n] = 0 ; zero p64 -------------
__global__ __launch_bounds__(256) void wprep_kernel(
    const float* __restrict__ W, unsigned short* __restrict__ Wt,
    float* __restrict__ cvec, int K, float* __restrict__ p64 /* 65536 floats */)
{
    const int n = blockIdx.x, k = threadIdx.x;
    if (k < K) Wt[(size_t)n * K + k] = f2bf(W[(size_t)k * DHID + n]);
    if (k == 0) cvec[n] = 0.0f;
    p64[n * 256 + k] = 0.0f;              // 256 blocks x 256 threads = both stats slabs
}

// ---------------- fused 64-slot stats reduce + BN-finalize + W prep ------------------------------
__global__ __launch_bounds__(256) void bnwprep_kernel(
    const float* __restrict__ p64, const float* __restrict__ gamma,
    const float* __restrict__ beta, const float* __restrict__ W,
    unsigned short* __restrict__ Wt, float* __restrict__ cvec)
{
    __shared__ float red[256];
    const int n = blockIdx.x, k = threadIdx.x;
    float s = 0.0f, q = 0.0f;
    #pragma unroll
    for (int p = 0; p < 64; ++p) {
        s += p64[p * 512 + k];
        q += p64[p * 512 + 256 + k];
    }
    const float nn = (float)NTOTAL;
    const float mean = s / nn;
    const float var = q / nn - mean * mean;
    const float sc = gamma[k] * rsqrtf(var + 1e-5f);
    const float sh = beta[k] - mean * sc;
    const float wv = W[(size_t)k * DHID + n];
    Wt[(size_t)n * DHID + k] = f2bf(sc * wv);
    red[k] = sh * wv;
    __syncthreads();
    for (int st = 128; st > 0; st >>= 1) {
        if (k < st) red[k] += red[k + st];
        __syncthreads();
    }
    if (k == 0) cvec[n] = red[0];
}

// ---------------- GEMM-1 (fp32 A, in-kernel cvt) + fused CSR builder (block 0) -------------------
__global__ __launch_bounds__(256) void gemm1_kernel(
    const float* __restrict__ x, const unsigned short* __restrict__ Wt,
    unsigned short* __restrict__ C,
    const int* __restrict__ ei, int E,
    int* __restrict__ offs, uint2* __restrict__ ecw,
    float* __restrict__ rowsum)
{
    __shared__ SMU sm;
    const int t = threadIdx.x;

    if (blockIdx.x == 0) {
        // ---------- builder (256 threads, 4 nodes/thread) ----------
        #pragma unroll
        for (int i = 0; i < 4; ++i) sm.b.scnt[t * 4 + i] = 1;
        __syncthreads();
        for (int e = t; e < E; e += 256) atomicAdd(&sm.b.scnt[ei[E + e]], 1);
        __syncthreads();
        int c[4]; int ssum = 0;
        #pragma unroll
        for (int i = 0; i < 4; ++i) { c[i] = sm.b.scnt[t * 4 + i]; ssum += c[i]; }
        sm.b.psA[t] = ssum;
        __syncthreads();
        int* src = sm.b.psA; int* dst = sm.b.psB;
        for (int d = 1; d < 256; d <<= 1) {          // 8 iters (even) -> result in psA
            dst[t] = src[t] + (t >= d ? src[t - d] : 0);
            __syncthreads();
            int* tmp = src; src = dst; dst = tmp;
        }
        int run = src[t] - ssum;                     // exclusive prefix of this 4-node group
        float di[4]; int pos[4];
        #pragma unroll
        for (int i = 0; i < 4; ++i) {
            offs[t * 4 + i] = run;
            di[i] = rsqrtf((float)c[i]);
            sm.b.sdinv[t * 4 + i] = di[i];
            pos[i] = run;
            run += c[i];
        }
        if (t == 255) offs[NNODES] = run;
        __syncthreads();
        #pragma unroll
        for (int i = 0; i < 4; ++i) {                // self loop first; cursor continues after it
            ecw[pos[i]] = make_uint2((unsigned)((t * 4 + i) * DHID * 2),
                                     __float_as_uint(di[i] * di[i]));
            sm.b.scnt[t * 4 + i] = pos[i] + 1;
            sm.b.fb[t * 4 + i] = di[i] * di[i];
        }
        __syncthreads();
        for (int e = t; e < E; e += 256) {
            const int sN = ei[e], dN = ei[E + e];
            const int p = atomicAdd(&sm.b.scnt[dN], 1);
            const float wv = sm.b.sdinv[sN] * sm.b.sdinv[dN];
            ecw[p] = make_uint2((unsigned)(sN * DHID * 2), __float_as_uint(wv));
            atomicAdd(&sm.b.fb[dN], wv);
        }
        __syncthreads();
        #pragma unroll
        for (int i = 0; i < 4; ++i) rowsum[t * 4 + i] = sm.b.fb[t * 4 + i];
        return;
    }

    // ---------- GEMM path ----------
    int m0, n0;
    gemm_decode(blockIdx.x - 1, m0, n0);
    const int K = FEAT_IN;

    const int w = t >> 6, lane = t & 63;
    const int wr = w >> 1, wc = w & 1;
    const int lr = lane & 15, lk = lane >> 4;
    const int srow = lane >> 3;
    const int seg_src = (lane & 7) ^ srow;           // inverse-swizzled source segment

    f32x4 acc[4][4];
    #pragma unroll
    for (int i = 0; i < 4; ++i)
        #pragma unroll
        for (int j = 0; j < 4; ++j)
            acc[i][j] = (f32x4){0.f, 0.f, 0.f, 0.f};

    const int r = t >> 1, kh = (t & 1) * 32;         // A-staging: row r, k-range [kh, kh+32)
    for (int s = 0; s < 2; ++s) {                    // K=128 -> 2 steps
        if (s > 0) __syncthreads();
        #pragma unroll
        for (int i = 0; i < 4; ++i) {
            const int row = (w * 4 + i) * 8 + srow;
            const unsigned short* gb = Wt + (size_t)(n0 + row) * K + s * GBK + seg_src * 8;
            __builtin_amdgcn_global_load_lds(
                (const __attribute__((address_space(1))) unsigned int*)gb,
                (__attribute__((address_space(3))) unsigned int*)&sm.g.sB[(w * 4 + i) * 512],
                16, 0, 0);
        }
        const float* ga = x + (size_t)(m0 + r) * K + s * GBK + kh;
        #pragma unroll
        for (int j = 0; j < 4; ++j) {
            const float4 v0 = *(const float4*)(ga + j * 8);
            const float4 v1 = *(const float4*)(ga + j * 8 + 4);
            us8 o;
            o[0] = f2bf(v0.x); o[1] = f2bf(v0.y); o[2] = f2bf(v0.z); o[3] = f2bf(v0.w);
            o[4] = f2bf(v1.x); o[5] = f2bf(v1.y); o[6] = f2bf(v1.z); o[7] = f2bf(v1.w);
            const int slot = ((kh >> 3) + j) ^ (r & 7);
            *(us8*)&sm.g.sA[r * 64 + slot * 8] = o;
        }
        __syncthreads();                             // drains B vmcnt + A lds writes
        const char* pa = (const char*)sm.g.sA;
        const char* pb = (const char*)sm.g.sB;
        #pragma unroll
        for (int ks = 0; ks < 2; ++ks) {
            bf16x8 af[4], bfv[4];
            #pragma unroll
            for (int f = 0; f < 4; ++f) {
                const int ra = wr * 64 + f * 16 + lr;
                af[f] = *(const bf16x8*)(pa + ra * 128 + ((ks * 64 + lk * 16) ^ ((ra & 7) << 4)));
                const int rb = wc * 64 + f * 16 + lr;
                bfv[f] = *(const bf16x8*)(pb + rb * 128 + ((ks * 64 + lk * 16) ^ ((rb & 7) << 4)));
            }
            #pragma unroll
            for (int mf = 0; mf < 4; ++mf)
                #pragma unroll
                for (int nf = 0; nf < 4; ++nf)
                    acc[mf][nf] = __builtin_amdgcn_mfma_f32_16x16x32_bf16(
                        af[mf], bfv[nf], acc[mf][nf], 0, 0, 0);
        }
    }

    #pragma unroll
    for (int mf = 0; mf < 4; ++mf) {
        const int rbase = m0 + wr * 64 + mf * 16 + lk * 4;
        #pragma unroll
        for (int nf = 0; nf < 4; ++nf) {
            const int c = n0 + wc * 64 + nf * 16 + lr;
            #pragma unroll
            for (int rr = 0; rr < 4; ++rr)
                C[(size_t)(rbase + rr) * DHID + c] = f2bf(acc[mf][nf][rr]);
        }
    }
}

// ---------------- MFMA GEMM (layers 2/3): C[M][256] = bf16(A @ Wt^T), A bf16 ---------------------
// SINGLE-buffered (32 KB LDS -> 4 blocks/CU): per K-step stage -> sync -> compute.
// m99/m114: explicit dbuf adds nothing at source level; the extra occupancy
// (2->4 blocks/CU) provides the inter-wave overlap that hides the barrier drain.
__global__ __launch_bounds__(256) void mgemm_kernel(
    const unsigned short* __restrict__ Ain,
    const unsigned short* __restrict__ Wt,
    unsigned short* __restrict__ C, int K)
{
    __shared__ unsigned short sA[128 * GBK];
    __shared__ unsigned short sB[128 * GBK];

    const int t = threadIdx.x;
    int m0, n0;
    gemm_decode(blockIdx.x, m0, n0);

    const int w = t >> 6, lane = t & 63;
    const int wr = w >> 1, wc = w & 1;
    const int lr = lane & 15, lk = lane >> 4;
    const int srow = lane >> 3;
    const int seg_src = (lane & 7) ^ srow;

    f32x4 acc[4][4];
    #pragma unroll
    for (int i = 0; i < 4; ++i)
        #pragma unroll
        for (int j = 0; j < 4; ++j)
            acc[i][j] = (f32x4){0.f, 0.f, 0.f, 0.f};

    const int nsteps = K >> 6;

    for (int s = 0; s < nsteps; ++s) {
        if (s > 0) __syncthreads();                  // previous compute done before overwrite
        #pragma unroll
        for (int i = 0; i < 4; ++i) {
            const int row = (w * 4 + i) * 8 + srow;
            const unsigned short* ga = Ain + (size_t)(m0 + row) * K + s * GBK + seg_src * 8;
            __builtin_amdgcn_global_load_lds(
                (const __attribute__((address_space(1))) unsigned int*)ga,
                (__attribute__((address_space(3))) unsigned int*)&sA[(w * 4 + i) * 512],
                16, 0, 0);
            const unsigned short* gb = Wt + (size_t)(n0 + row) * K + s * GBK + seg_src * 8;
            __builtin_amdgcn_global_load_lds(
                (const __attribute__((address_space(1))) unsigned int*)gb,
                (__attribute__((address_space(3))) unsigned int*)&sB[(w * 4 + i) * 512],
                16, 0, 0);
        }
        __syncthreads();                             // drains vmcnt (loads landed)
        const char* pa = (const char*)sA;
        const char* pb = (const char*)sB;
        #pragma unroll
        for (int ks = 0; ks < 2; ++ks) {
            bf16x8 af[4], bfv[4];
            #pragma unroll
            for (int f = 0; f < 4; ++f) {
                const int ra = wr * 64 + f * 16 + lr;
                af[f] = *(const bf16x8*)(pa + ra * 128 + ((ks * 64 + lk * 16) ^ ((ra & 7) << 4)));
                const int rb = wc * 64 + f * 16 + lr;
                bfv[f] = *(const bf16x8*)(pb + rb * 128 + ((ks * 64 + lk * 16) ^ ((rb & 7) << 4)));
            }
            #pragma unroll
            for (int mf = 0; mf < 4; ++mf)
                #pragma unroll
                for (int nf = 0; nf < 4; ++nf)
                    acc[mf][nf] = __builtin_amdgcn_mfma_f32_16x16x32_bf16(
                        af[mf], bfv[nf], acc[mf][nf], 0, 0, 0);
        }
    }

    #pragma unroll
    for (int mf = 0; mf < 4; ++mf) {
        const int rbase = m0 + wr * 64 + mf * 16 + lk * 4;
        #pragma unroll
        for (int nf = 0; nf < 4; ++nf) {
            const int c = n0 + wc * 64 + nf * 16 + lr;
            #pragma unroll
            for (int rr = 0; rr < 4; ++rr)
                C[(size_t)(rbase + rr) * DHID + c] = f2bf(acc[mf][nf][rr]);
        }
    }
}

// ---------------- SpMM: h = relu(Anorm @ hw + rowsum*c + b), 32 nodes/block, 512 threads ---------
#define NB 32
#define ECAPB 512

template<bool STATS, bool OUTF32>
__global__ __launch_bounds__(512) void spmm_kernel(
    const unsigned short* __restrict__ hw, const float* __restrict__ bias,
    const float* __restrict__ rowsum, const float* __restrict__ cvec,
    void* __restrict__ hout, float* __restrict__ p64,
    const int* __restrict__ offs, const uint2* __restrict__ ecw)
{
    __shared__ uint2 sew[ECAPB];
    __shared__ int soff[NB + 1];
    __shared__ float srs[NB];
    __shared__ float spartS[8][256];
    __shared__ float spartQ[8][256];

    const int b = blockIdx.x;                 // 4096 blocks
    const int xcd = b & 7;
    const int idx = b >> 3;
    const int g  = (idx >> 5) * 8 + xcd;      // all 32 blocks of graph g on one XCD
    const int nb = (idx & 31) * NB;
    const int t = threadIdx.x;
    const int w = t >> 6, l = t & 63;
    const int f0 = l * 4;
    const char* __restrict__ hb =
        (const char*)(hw + (size_t)g * NNODES * DHID) + (size_t)f0 * 2;

    if (t <= NB) soff[t] = offs[nb + t];
    if (t < NB)  srs[t] = rowsum[nb + t];
    __syncthreads();
    const int base = soff[0];
    const int tot = soff[NB] - base;          // ~290, cap 512
    for (int e = t; e < tot; e += 512) sew[e] = ecw[base + e];
    __syncthreads();

    const float4 bv = *(const float4*)(bias + f0);
    const float4 cv = *(const float4*)(cvec + f0);
    float ps0=0, ps1=0, ps2=0, ps3=0, pq0=0, pq1=0, pq2=0, pq3=0;

    #pragma unroll 1
    for (int j = 0; j < 4; ++j) {
        const int i = w * 4 + j;
        const int s = soff[i] - base, e = soff[i + 1] - base;
        const float rs = srs[i];
        float a0=0, a1=0, a2=0, a3=0;
        int k = s;
        #pragma unroll 1
        for (; k + 4 <= e; k += 4) {
            const uint2 p0 = sew[k+0], p1 = sew[k+1], p2 = sew[k+2], p3 = sew[k+3];
            const uint2 u0 = *(const uint2*)(hb + p0.x);
            const uint2 u1 = *(const uint2*)(hb + p1.x);
            const uint2 u2 = *(const uint2*)(hb + p2.x);
            const uint2 u3 = *(const uint2*)(hb + p3.x);
            const float w0 = __uint_as_float(p0.y), w1 = __uint_as_float(p1.y);
            const float w2 = __uint_as_float(p2.y), w3 = __uint_as_float(p3.y);
            a0 = fmaf(w0, blo(u0.x), a0); a1 = fmaf(w0, bhi(u0.x), a1);
            a2 = fmaf(w0, blo(u0.y), a2); a3 = fmaf(w0, bhi(u0.y), a3);
            a0 = fmaf(w1, blo(u1.x), a0); a1 = fmaf(w1, bhi(u1.x), a1);
            a2 = fmaf(w1, blo(u1.y), a2); a3 = fmaf(w1, bhi(u1.y), a3);
            a0 = fmaf(w2, blo(u2.x), a0); a1 = fmaf(w2, bhi(u2.x), a1);
            a2 = fmaf(w2, blo(u2.y), a2); a3 = fmaf(w2, bhi(u2.y), a3);
            a0 = fmaf(w3, blo(u3.x), a0); a1 = fmaf(w3, bhi(u3.x), a1);
            a2 = fmaf(w3, blo(u3.y), a2); a3 = fmaf(w3, bhi(u3.y), a3);
        }
        #pragma unroll 1
        for (; k < e; ++k) {
            const uint2 p = sew[k];
            const uint2 u = *(const uint2*)(hb + p.x);
            const float wk = __uint_as_float(p.y);
            a0 = fmaf(wk, blo(u.x), a0); a1 = fmaf(wk, bhi(u.x), a1);
            a2 = fmaf(wk, blo(u.y), a2); a3 = fmaf(wk, bhi(u.y), a3);
        }

        const float v0 = fmaxf(fmaf(rs, cv.x, a0) + bv.x, 0.0f);
        const float v1 = fmaxf(fmaf(rs, cv.y, a1) + bv.y, 0.0f);
        const float v2 = fmaxf(fmaf(rs, cv.z, a2) + bv.z, 0.0f);
        const float v3 = fmaxf(fmaf(rs, cv.w, a3) + bv.w, 0.0f);
        const size_t orow = (size_t)g * NNODES + nb + i;
        if (OUTF32) {
            *(float4*)((float*)hout + orow * DHID + f0) = make_float4(v0, v1, v2, v3);
        } else {
            us4 o; o[0] = f2bf(v0); o[1] = f2bf(v1); o[2] = f2bf(v2); o[3] = f2bf(v3);
            *(us4*)((unsigned short*)hout + orow * DHID + f0) = o;
        }
        if (STATS) {
            ps0 += v0; ps1 += v1; ps2 += v2; ps3 += v3;
            pq0 += v0*v0; pq1 += v1*v1; pq2 += v2*v2; pq3 += v3*v3;
        }
    }

    if (STATS) {
        spartS[w][f0+0] = ps0; spartS[w][f0+1] = ps1; spartS[w][f0+2] = ps2; spartS[w][f0+3] = ps3;
        spartQ[w][f0+0] = pq0; spartQ[w][f0+1] = pq1; spartQ[w][f0+2] = pq2; spartQ[w][f0+3] = pq3;
        __syncthreads();
        if (t < 256) {
            float ss = 0.0f, sq = 0.0f;
            #pragma unroll
            for (int p = 0; p < 8; ++p) { ss += spartS[p][t]; sq += spartQ[p][t]; }
            float* slot = p64 + (size_t)(b & 63) * 512;
            atomicAdd(&slot[t], ss);
            atomicAdd(&slot[256 + t], sq);
        }
    }
}

// ---------------- launch -------------------------------------------------------------------------
extern "C" void kernel_launch(void* const* d_in, const int* in_sizes, int n_in,
                              void* d_out, int out_size, void* d_ws, size_t ws_size,
                              hipStream_t stream)
{
    const float* x      = (const float*)d_in[0];
    const int*   ei     = (const int*)d_in[1];
    const float* W1     = (const float*)d_in[3];
    const float* b1     = (const float*)d_in[4];
    const float* W2     = (const float*)d_in[5];
    const float* b2     = (const float*)d_in[6];
    const float* W3     = (const float*)d_in[7];
    const float* b3     = (const float*)d_in[8];
    const float* gamma1 = (const float*)d_in[9];
    const float* beta1  = (const float*)d_in[10];
    const float* gamma2 = (const float*)d_in[11];
    const float* beta2  = (const float*)d_in[12];
    float* out = (float*)d_out;

    const int E = in_sizes[1] / 2;   // 8192

    // workspace layout (total ~135 MB + meta)
    char* w = (char*)d_ws;
    unsigned short* hA = (unsigned short*)w;                 // h bf16 (67 MB)
    unsigned short* hw = (unsigned short*)(w + 67108864);    // 67 MB
    char* meta = w + 134217728;
    float* p64a   = (float*)meta;          meta += 64 * 512 * 4;   // layer-1 stats slots
    float* p64b   = (float*)meta;          meta += 64 * 512 * 4;   // layer-2 stats slots (contiguous)
    int*   offs   = (int*)meta;            meta += 4352;
    uint2* ecw    = (uint2*)meta;          meta += ECAP * 8;
    float* rowsum = (float*)meta;          meta += NNODES * 4;
    float* cvec1  = (float*)meta;          meta += 256 * 4;
    float* cvec2  = (float*)meta;          meta += 256 * 4;
    float* cvec3  = (float*)meta;          meta += 256 * 4;
    unsigned short* wt1 = (unsigned short*)meta;  meta += 256 * 128 * 2;
    unsigned short* wt2 = (unsigned short*)meta;  meta += 256 * 256 * 2;
    unsigned short* wt3 = (unsigned short*)meta;  meta += 256 * 256 * 2;

    const int GG = 2048;                 // GEMM blocks (XCD-affine decode in-kernel)
    const int P  = NTOTAL / NB;          // 4096 spmm blocks

    wprep_kernel<<<DHID, 256, 0, stream>>>(W1, wt1, cvec1, FEAT_IN, p64a);  // also zeroes p64a+p64b

    // Layer 1: GEMM (x fp32 converted in-kernel) + CSR builder fused as block 0
    gemm1_kernel<<<GG + 1, 256, 0, stream>>>(x, wt1, hw, ei, E, offs, ecw, rowsum);
    spmm_kernel<true, false><<<P, 512, 0, stream>>>(hw, b1, rowsum, cvec1, hA, p64a, offs, ecw);
    bnwprep_kernel<<<DHID, 256, 0, stream>>>(p64a, gamma1, beta1, W2, wt2, cvec2);

    // Layer 2
    mgemm_kernel<<<GG, 256, 0, stream>>>(hA, wt2, hw, DHID);
    spmm_kernel<true, false><<<P, 512, 0, stream>>>(hw, b2, rowsum, cvec2, hA, p64b, offs, ecw);
    bnwprep_kernel<<<DHID, 256, 0, stream>>>(p64b, gamma2, beta2, W3, wt3, cvec3);

    // Layer 3 (fp32 output, no stats)
    mgemm_kernel<<<GG, 256, 0, stream>>>(hA, wt3, hw, DHID);
    spmm_kernel<false, true><<<P, 512, 0, stream>>>(hw, b3, rowsum, cvec3, out, nullptr, offs, ecw);
}